// Round 1
// baseline (2657.303 us; speedup 1.0000x reference)
//
#include <hip/hip_runtime.h>
#include <math.h>

// ---------------- problem constants ----------------
#define NB 2
#define NSEQ 4380
#define NPATH 284
#define NHIST 4096
#define DIM 512
#define HEADS 8
#define DHEAD 256
#define INNER 2048
#define N3 6144
#define KSZ 33
#define SCALE_F 0.0625f
#define NBH 16
#define M1 8760   // NB*NSEQ

// ---------------- d_out offsets (floats) ----------------
#define OUT0_OFF 0            // (2,4380,2048)
#define OUT1_OFF 17940480     // attn_pathways (2,8,284,284)
#define OUT2_OFF 19230976     // cross_attn_pathways (2,8,284,4096)
#define OUT3_OFF 37843200     // pre-softmax cross_attn_histology (2,8,4096,284)

// ---------------- ws offsets (floats) ----------------
#define QW_OFF 0
#define KW_OFF 17940480
#define VW_OFF 35880960
#define ST2_OFF 53821440      // 4544 rows * 2 (m, 1/s)
#define ST3_OFF 53830528      // 65536 rows * 2

// =====================================================================
// Kernel 1: qkv = x @ w_qkv, scatter to q/k/v ws (head-major), scale q
// =====================================================================
__global__ void k_qkv_gemm(const float* __restrict__ x, const float* __restrict__ w,
                           float* __restrict__ qws, float* __restrict__ kws,
                           float* __restrict__ vws)
{
    __shared__ float As[16][65];
    __shared__ float Bs[16][65];
    const int tid = threadIdx.x;
    const int tx = tid & 15, ty = tid >> 4;
    const int m0 = blockIdx.y * 64;
    const int n0 = blockIdx.x * 64;
    float acc[4][4] = {};

    for (int k0 = 0; k0 < DIM; k0 += 16) {
        #pragma unroll
        for (int i = 0; i < 4; ++i) {
            int l = tid + i * 256;
            int r = l >> 4, c = l & 15;
            int m = m0 + r;
            As[c][r] = (m < M1) ? x[(size_t)m * DIM + k0 + c] : 0.f;
        }
        #pragma unroll
        for (int i = 0; i < 4; ++i) {
            int l = tid + i * 256;
            int r = l >> 6, c = l & 63;
            Bs[r][c] = w[(size_t)(k0 + r) * N3 + n0 + c];
        }
        __syncthreads();
        #pragma unroll
        for (int kk = 0; kk < 16; ++kk) {
            float a[4], b[4];
            #pragma unroll
            for (int i = 0; i < 4; ++i) a[i] = As[kk][ty * 4 + i];
            #pragma unroll
            for (int j = 0; j < 4; ++j) b[j] = Bs[kk][tx * 4 + j];
            #pragma unroll
            for (int i = 0; i < 4; ++i)
                #pragma unroll
                for (int j = 0; j < 4; ++j)
                    acc[i][j] += a[i] * b[j];
        }
        __syncthreads();
    }

    #pragma unroll
    for (int i = 0; i < 4; ++i) {
        int m = m0 + ty * 4 + i;
        if (m >= M1) continue;
        int b = m / NSEQ, n = m % NSEQ;
        #pragma unroll
        for (int j = 0; j < 4; ++j) {
            int col = n0 + tx * 4 + j;        // 0..6143
            int part = col >> 11;             // 0=q 1=k 2=v
            int within = col & 2047;
            int h = within >> 8, d = within & 255;
            size_t idx = ((size_t)(b * HEADS + h) * NSEQ + n) * DHEAD + d;
            float val = acc[i][j];
            if (part == 0)      qws[idx] = val * SCALE_F;
            else if (part == 1) kws[idx] = val;
            else                vws[idx] = val;
        }
    }
}

// =====================================================================
// Kernel 2a: scores vs k_p :  q(all rows) @ k_p^T  -> out1 (rows<284), out3
// =====================================================================
__global__ void k_scores_kp(const float* __restrict__ qws, const float* __restrict__ kws,
                            float* __restrict__ out1, float* __restrict__ out3)
{
    __shared__ float As[16][65];   // As[k][i]
    __shared__ float Bs[16][65];   // Bs[k][j]
    const int tid = threadIdx.x;
    const int tx = tid & 15, ty = tid >> 4;
    const int bh = blockIdx.z;
    const int i0 = blockIdx.y * 64;
    const int j0 = blockIdx.x * 64;
    const float* A  = qws + (size_t)bh * NSEQ * DHEAD;
    const float* Kp = kws + (size_t)bh * NSEQ * DHEAD;   // rows 0..283
    float acc[4][4] = {};

    for (int k0 = 0; k0 < DHEAD; k0 += 16) {
        #pragma unroll
        for (int i = 0; i < 4; ++i) {
            int l = tid + i * 256;
            int r = l >> 4, c = l & 15;
            int row = i0 + r;
            As[c][r] = (row < NSEQ) ? A[(size_t)row * DHEAD + k0 + c] : 0.f;
        }
        #pragma unroll
        for (int i = 0; i < 4; ++i) {
            int l = tid + i * 256;
            int jj = l >> 4, c = l & 15;
            int row = j0 + jj;
            Bs[c][jj] = (row < NPATH) ? Kp[(size_t)row * DHEAD + k0 + c] : 0.f;
        }
        __syncthreads();
        #pragma unroll
        for (int kk = 0; kk < 16; ++kk) {
            float a[4], b[4];
            #pragma unroll
            for (int i = 0; i < 4; ++i) a[i] = As[kk][ty * 4 + i];
            #pragma unroll
            for (int j = 0; j < 4; ++j) b[j] = Bs[kk][tx * 4 + j];
            #pragma unroll
            for (int i = 0; i < 4; ++i)
                #pragma unroll
                for (int j = 0; j < 4; ++j)
                    acc[i][j] += a[i] * b[j];
        }
        __syncthreads();
    }

    #pragma unroll
    for (int i = 0; i < 4; ++i) {
        int ig = i0 + ty * 4 + i;
        if (ig >= NSEQ) continue;
        #pragma unroll
        for (int j = 0; j < 4; ++j) {
            int jg = j0 + tx * 4 + j;
            if (jg >= NPATH) continue;
            if (ig < NPATH)
                out1[((size_t)bh * NPATH + ig) * NPATH + jg] = acc[i][j];
            else
                out3[((size_t)bh * NHIST + (ig - NPATH)) * NPATH + jg] = acc[i][j];
        }
    }
}

// =====================================================================
// Kernel 2b: out2 = q_p @ k_h^T   (284 x 4096 per bh)
// =====================================================================
__global__ void k_scores_kh(const float* __restrict__ qws, const float* __restrict__ kws,
                            float* __restrict__ out2)
{
    __shared__ float As[16][65];
    __shared__ float Bs[16][65];
    const int tid = threadIdx.x;
    const int tx = tid & 15, ty = tid >> 4;
    const int bh = blockIdx.z;
    const int i0 = blockIdx.y * 64;
    const int j0 = blockIdx.x * 64;
    const float* A  = qws + (size_t)bh * NSEQ * DHEAD;                    // rows 0..283
    const float* Kh = kws + ((size_t)bh * NSEQ + NPATH) * DHEAD;          // rows 0..4095
    float acc[4][4] = {};

    for (int k0 = 0; k0 < DHEAD; k0 += 16) {
        #pragma unroll
        for (int i = 0; i < 4; ++i) {
            int l = tid + i * 256;
            int r = l >> 4, c = l & 15;
            int row = i0 + r;
            As[c][r] = (row < NPATH) ? A[(size_t)row * DHEAD + k0 + c] : 0.f;
        }
        #pragma unroll
        for (int i = 0; i < 4; ++i) {
            int l = tid + i * 256;
            int jj = l >> 4, c = l & 15;
            int row = j0 + jj;   // < 4096 always
            Bs[c][jj] = Kh[(size_t)row * DHEAD + k0 + c];
        }
        __syncthreads();
        #pragma unroll
        for (int kk = 0; kk < 16; ++kk) {
            float a[4], b[4];
            #pragma unroll
            for (int i = 0; i < 4; ++i) a[i] = As[kk][ty * 4 + i];
            #pragma unroll
            for (int j = 0; j < 4; ++j) b[j] = Bs[kk][tx * 4 + j];
            #pragma unroll
            for (int i = 0; i < 4; ++i)
                #pragma unroll
                for (int j = 0; j < 4; ++j)
                    acc[i][j] += a[i] * b[j];
        }
        __syncthreads();
    }

    #pragma unroll
    for (int i = 0; i < 4; ++i) {
        int ig = i0 + ty * 4 + i;
        if (ig >= NPATH) continue;
        #pragma unroll
        for (int j = 0; j < 4; ++j) {
            int jg = j0 + tx * 4 + j;
            out2[((size_t)bh * NPATH + ig) * NHIST + jg] = acc[i][j];
        }
    }
}

// =====================================================================
// Kernel 3a: row stats (max, 1/sumexp) for out2 rows (len 4096)
// =====================================================================
__global__ void k_stats2(const float* __restrict__ sc, float* __restrict__ st)
{
    __shared__ float red[4];
    const int row = blockIdx.x;                 // bh*284 + i  (4544 rows)
    const int tid = threadIdx.x;
    const float* p = sc + (size_t)row * NHIST;

    float m = -1e30f;
    for (int j = tid; j < NHIST; j += 256) m = fmaxf(m, p[j]);
    #pragma unroll
    for (int o = 32; o >= 1; o >>= 1) m = fmaxf(m, __shfl_xor(m, o));
    if ((tid & 63) == 0) red[tid >> 6] = m;
    __syncthreads();
    m = fmaxf(fmaxf(red[0], red[1]), fmaxf(red[2], red[3]));

    float s = 0.f;
    for (int j = tid; j < NHIST; j += 256) s += expf(p[j] - m);
    #pragma unroll
    for (int o = 32; o >= 1; o >>= 1) s += __shfl_xor(s, o);
    __syncthreads();
    if ((tid & 63) == 0) red[tid >> 6] = s;
    __syncthreads();
    if (tid == 0) {
        s = red[0] + red[1] + red[2] + red[3];
        st[(size_t)row * 2]     = m;
        st[(size_t)row * 2 + 1] = 1.f / s;
    }
}

// =====================================================================
// Kernel 3b: row stats for out3 rows (len 284), one wave per row
// =====================================================================
__global__ void k_stats3(const float* __restrict__ sc, float* __restrict__ st)
{
    const int row  = blockIdx.x * 4 + (threadIdx.x >> 6);   // 65536 rows
    const int lane = threadIdx.x & 63;
    const float* p = sc + (size_t)row * NPATH;

    float m = -1e30f;
    for (int j = lane; j < NPATH; j += 64) m = fmaxf(m, p[j]);
    #pragma unroll
    for (int o = 32; o >= 1; o >>= 1) m = fmaxf(m, __shfl_xor(m, o));

    float s = 0.f;
    for (int j = lane; j < NPATH; j += 64) s += expf(p[j] - m);
    #pragma unroll
    for (int o = 32; o >= 1; o >>= 1) s += __shfl_xor(s, o);

    if (lane == 0) {
        st[(size_t)row * 2]     = m;
        st[(size_t)row * 2 + 1] = 1.f / s;
    }
}

// =====================================================================
// Kernel 4: out rows 0..283 = softmax(out2) @ v_h
// =====================================================================
__global__ void k_out_path(const float* __restrict__ sc2, const float* __restrict__ st2,
                           const float* __restrict__ vws, float* __restrict__ out0)
{
    __shared__ float As[16][65];   // As[k][i] = P
    __shared__ float Bs[16][65];   // Bs[k][d]
    const int tid = threadIdx.x;
    const int tx = tid & 15, ty = tid >> 4;
    const int bh = blockIdx.z;
    const int i0 = blockIdx.y * 64;
    const int d0 = blockIdx.x * 64;
    const int b = bh >> 3, h = bh & 7;
    float acc[4][4] = {};

    for (int k0 = 0; k0 < NHIST; k0 += 16) {
        #pragma unroll
        for (int i = 0; i < 4; ++i) {
            int l = tid + i * 256;
            int r = l >> 4, c = l & 15;
            int row = i0 + r;
            float val = 0.f;
            if (row < NPATH) {
                size_t srow = (size_t)bh * NPATH + row;
                float raw = sc2[srow * NHIST + k0 + c];
                float mm  = st2[srow * 2];
                float is  = st2[srow * 2 + 1];
                val = expf(raw - mm) * is;
            }
            As[c][r] = val;
        }
        #pragma unroll
        for (int i = 0; i < 4; ++i) {
            int l = tid + i * 256;
            int r = l >> 6, c = l & 63;
            Bs[r][c] = vws[((size_t)bh * NSEQ + NPATH + k0 + r) * DHEAD + d0 + c];
        }
        __syncthreads();
        #pragma unroll
        for (int kk = 0; kk < 16; ++kk) {
            float a[4], bb[4];
            #pragma unroll
            for (int i = 0; i < 4; ++i) a[i] = As[kk][ty * 4 + i];
            #pragma unroll
            for (int j = 0; j < 4; ++j) bb[j] = Bs[kk][tx * 4 + j];
            #pragma unroll
            for (int i = 0; i < 4; ++i)
                #pragma unroll
                for (int j = 0; j < 4; ++j)
                    acc[i][j] += a[i] * bb[j];
        }
        __syncthreads();
    }

    #pragma unroll
    for (int i = 0; i < 4; ++i) {
        int ig = i0 + ty * 4 + i;
        if (ig >= NPATH) continue;
        #pragma unroll
        for (int j = 0; j < 4; ++j) {
            int d = d0 + tx * 4 + j;
            out0[((size_t)(b * NSEQ + ig)) * INNER + h * DHEAD + d] = acc[i][j];
        }
    }
}

// =====================================================================
// Kernel 5: out rows 284.. = softmax(out3) @ v_p
// =====================================================================
__global__ void k_out_hist(const float* __restrict__ sc3, const float* __restrict__ st3,
                           const float* __restrict__ vws, float* __restrict__ out0)
{
    __shared__ float As[16][65];
    __shared__ float Bs[16][65];
    const int tid = threadIdx.x;
    const int tx = tid & 15, ty = tid >> 4;
    const int bh = blockIdx.z;
    const int i0 = blockIdx.y * 64;
    const int d0 = blockIdx.x * 64;
    const int b = bh >> 3, h = bh & 7;
    float acc[4][4] = {};

    for (int k0 = 0; k0 < NPATH; k0 += 16) {
        #pragma unroll
        for (int i = 0; i < 4; ++i) {
            int l = tid + i * 256;
            int r = l >> 4, c = l & 15;
            int row = i0 + r;        // < 4096 always
            int kc = k0 + c;
            float val = 0.f;
            if (kc < NPATH) {
                size_t srow = (size_t)bh * NHIST + row;
                float raw = sc3[srow * NPATH + kc];
                float mm  = st3[srow * 2];
                float is  = st3[srow * 2 + 1];
                val = expf(raw - mm) * is;
            }
            As[c][r] = val;
        }
        #pragma unroll
        for (int i = 0; i < 4; ++i) {
            int l = tid + i * 256;
            int r = l >> 6, c = l & 63;
            int kr = k0 + r;
            Bs[r][c] = (kr < NPATH) ? vws[((size_t)bh * NSEQ + kr) * DHEAD + d0 + c] : 0.f;
        }
        __syncthreads();
        #pragma unroll
        for (int kk = 0; kk < 16; ++kk) {
            float a[4], bb[4];
            #pragma unroll
            for (int i = 0; i < 4; ++i) a[i] = As[kk][ty * 4 + i];
            #pragma unroll
            for (int j = 0; j < 4; ++j) bb[j] = Bs[kk][tx * 4 + j];
            #pragma unroll
            for (int i = 0; i < 4; ++i)
                #pragma unroll
                for (int j = 0; j < 4; ++j)
                    acc[i][j] += a[i] * bb[j];
        }
        __syncthreads();
    }

    #pragma unroll
    for (int i = 0; i < 4; ++i) {
        int ig = i0 + ty * 4 + i;    // 0..4095
        #pragma unroll
        for (int j = 0; j < 4; ++j) {
            int d = d0 + tx * 4 + j;
            out0[((size_t)(b * NSEQ + NPATH + ig)) * INNER + h * DHEAD + d] = acc[i][j];
        }
    }
}

// =====================================================================
// Kernel 6: depthwise conv over sequence axis, accumulate into out0
// =====================================================================
__global__ void k_conv(const float* __restrict__ vws, const float* __restrict__ wconv,
                       float* __restrict__ out0)
{
    __shared__ float lv[64][DHEAD];   // 64 rows halo tile, 64 KB
    const int bh = blockIdx.z;
    const int b = bh >> 3, h = bh & 7;
    const int n0 = blockIdx.y * 32;
    const int d = threadIdx.x;
    const float* vb = vws + (size_t)bh * NSEQ * DHEAD;

    for (int r = 0; r < 64; ++r) {
        int n = n0 - 16 + r;
        lv[r][d] = (n >= 0 && n < NSEQ) ? vb[(size_t)n * DHEAD + d] : 0.f;
    }
    __syncthreads();

    float wc[KSZ];
    #pragma unroll
    for (int t = 0; t < KSZ; ++t) wc[t] = wconv[h * KSZ + t];

    for (int i = 0; i < 32; ++i) {
        int n = n0 + i;
        if (n >= NSEQ) break;
        float acc = 0.f;
        #pragma unroll
        for (int t = 0; t < KSZ; ++t) acc += lv[i + t][d] * wc[t];
        out0[((size_t)(b * NSEQ + n)) * INNER + h * DHEAD + d] += acc;
    }
}

// =====================================================================
extern "C" void kernel_launch(void* const* d_in, const int* in_sizes, int n_in,
                              void* d_out, int out_size, void* d_ws, size_t ws_size,
                              hipStream_t stream)
{
    const float* x     = (const float*)d_in[0];
    const float* wqkv  = (const float*)d_in[1];
    const float* wconv = (const float*)d_in[2];
    float* out = (float*)d_out;
    float* ws  = (float*)d_ws;

    float* qws = ws + QW_OFF;
    float* kws = ws + KW_OFF;
    float* vws = ws + VW_OFF;
    float* st2 = ws + ST2_OFF;
    float* st3 = ws + ST3_OFF;

    float* out0 = out + OUT0_OFF;
    float* out1 = out + OUT1_OFF;
    float* out2 = out + OUT2_OFF;
    float* out3 = out + OUT3_OFF;

    dim3 blk(256);

    // 1. qkv GEMM  (M=8760, N=6144, K=512)
    k_qkv_gemm<<<dim3(96, 137), blk, 0, stream>>>(x, wqkv, qws, kws, vws);

    // 2a. q @ k_p^T -> out1/out3
    k_scores_kp<<<dim3(5, 69, NBH), blk, 0, stream>>>(qws, kws, out1, out3);

    // 2b. q_p @ k_h^T -> out2
    k_scores_kh<<<dim3(64, 5, NBH), blk, 0, stream>>>(qws, kws, out2);

    // 3. softmax row stats
    k_stats2<<<dim3(NBH * NPATH), blk, 0, stream>>>(out2, st2);
    k_stats3<<<dim3(NBH * NHIST / 4), blk, 0, stream>>>(out3, st3);

    // 4. out_pathways = softmax(out2) @ v_h
    k_out_path<<<dim3(4, 5, NBH), blk, 0, stream>>>(out2, st2, vws, out0);

    // 5. out_histology = softmax(out3) @ v_p
    k_out_hist<<<dim3(4, 64, NBH), blk, 0, stream>>>(out3, st3, vws, out0);

    // 6. depthwise conv, accumulate
    k_conv<<<dim3(1, 137, NBH), blk, 0, stream>>>(vws, wconv, out0);
}

// Round 3
// 652.832 us; speedup vs baseline: 4.0704x; 4.0704x over previous
//
#include <hip/hip_runtime.h>
#include <math.h>

typedef unsigned short u16;
typedef unsigned int   u32;
typedef __attribute__((ext_vector_type(8))) short bf16x8;
typedef __attribute__((ext_vector_type(4))) float f32x4;
typedef __attribute__((ext_vector_type(4))) u16   u16x4;

// ---------------- problem constants ----------------
#define NB 2
#define NSEQ 4380
#define NPATH 284
#define NHIST 4096
#define DIM 512
#define HEADS 8
#define DHEAD 256
#define INNER 2048
#define N3 6144
#define KSZ 33
#define SCALE_F 0.0625f
#define NBH 16
#define M1 8760   // NB*NSEQ

// ---------------- d_out offsets (floats) ----------------
#define OUT0_OFF 0            // (2,4380,2048)
#define OUT1_OFF 17940480     // attn_pathways (2,8,284,284)
#define OUT2_OFF 19230976     // cross_attn_pathways (2,8,284,4096)
#define OUT3_OFF 37843200     // pre-softmax cross_attn_histology (2,8,4096,284)

// ---------------- ws offsets (bytes) ----------------
#define XB_OFF   0u                      // bf16 x           [8760][512]
#define WB_OFF   8970240u                // bf16 w^T         [6144][512]
#define QW_OFF   15261696u               // bf16 q head-major[16][4380][256]
#define KW_OFF   51142656u               // bf16 k
#define VW_OFF   87023616u               // bf16 v  [bh][n][d]   (conv)
#define VT_OFF   122904576u              // bf16 v^T[bh][d][n]   (PV B-operand)
#define ST2_OFF  158785536u              // f32 stats out2 rows (4544*2)
#define ST3_OFF  158821888u              // f32 stats out3 rows (65536*2)

__device__ __forceinline__ u16 f2b(float f) {
    u32 u = __float_as_uint(f);
    u += 0x7fffu + ((u >> 16) & 1u);
    return (u16)(u >> 16);
}
__device__ __forceinline__ float b2f(u16 u) {
    return __uint_as_float(((u32)u) << 16);
}

__device__ __forceinline__ void async_cp16(const u16* g, u16* l) {
    __builtin_amdgcn_global_load_lds(
        (const __attribute__((address_space(1))) void*)g,
        (__attribute__((address_space(3))) void*)l,
        16, 0, 0);
}

// Stage a 128x32 bf16 tile [row][k] from row-major g (ld elems) via global_load_lds.
// rows row0..row0+127 clamped to rowmax (dup rows; outputs guarded at store).
__device__ __forceinline__ void stage128x32(const u16* __restrict__ g, int ld,
                                            int row0, int rowmax, int k0,
                                            u16* lds)
{
    const int t = threadIdx.x;          // 0..255
    const int w = t >> 6;
    #pragma unroll
    for (int j = 0; j < 2; ++j) {
        int c = j * 256 + t;            // chunk 0..511
        int r = c >> 2, kg = c & 3;
        int row = row0 + r; if (row > rowmax) row = rowmax;
        const u16* gp = g + (size_t)row * ld + k0 + kg * 8;
        async_cp16(gp, lds + (size_t)(j * 256 + w * 64) * 8);
    }
}

// 128x128 block, 4 waves (2x2 of 64x64), one BK=32 step: 4+4 ds_read_b128, 16 MFMA
__device__ __forceinline__ void compute_step(const u16* shA, const u16* shB,
                                             int wm, int wn, int lane,
                                             f32x4 acc[4][4])
{
    const int lr = lane & 15, lk = (lane >> 4) * 8;
    bf16x8 a[4], b[4];
    #pragma unroll
    for (int i = 0; i < 4; ++i)
        a[i] = *(const bf16x8*)(shA + (size_t)(wm * 64 + i * 16 + lr) * 32 + lk);
    #pragma unroll
    for (int j = 0; j < 4; ++j)
        b[j] = *(const bf16x8*)(shB + (size_t)(wn * 64 + j * 16 + lr) * 32 + lk);
    #pragma unroll
    for (int i = 0; i < 4; ++i)
        #pragma unroll
        for (int j = 0; j < 4; ++j)
            acc[i][j] = __builtin_amdgcn_mfma_f32_16x16x32_bf16(a[i], b[j], acc[i][j], 0, 0, 0);
}

// =====================================================================
// converts
// =====================================================================
__global__ void k_cvt(const float* __restrict__ src, u16* __restrict__ dst, int n4)
{
    int i = blockIdx.x * 256 + threadIdx.x;
    if (i >= n4) return;
    f32x4 f = *(const f32x4*)(src + (size_t)i * 4);
    u16x4 o;
    #pragma unroll
    for (int k = 0; k < 4; ++k) o[k] = f2b(f[k]);
    *(u16x4*)(dst + (size_t)i * 4) = o;
}

__global__ void k_cvt_wT(const float* __restrict__ w, u16* __restrict__ wb)
{
    __shared__ float tile[32][33];
    const int n0 = blockIdx.x * 32, k0 = blockIdx.y * 32;
    const int tx = threadIdx.x & 31, ty = threadIdx.x >> 5;   // ty 0..7
    #pragma unroll
    for (int r = 0; r < 32; r += 8)
        tile[ty + r][tx] = w[(size_t)(k0 + ty + r) * N3 + n0 + tx];
    __syncthreads();
    #pragma unroll
    for (int r = 0; r < 32; r += 8)
        wb[(size_t)(n0 + ty + r) * DIM + k0 + tx] = f2b(tile[tx][ty + r]);
}

// =====================================================================
// qkv GEMM: xb[8760][512] @ wb^T -> scatter q/k/v (bf16)
// =====================================================================
__global__ void k_qkv(const u16* __restrict__ xb, const u16* __restrict__ wb,
                      u16* __restrict__ qws, u16* __restrict__ kws,
                      u16* __restrict__ vws, u16* __restrict__ vt)
{
    __shared__ u16 sh[2][2][4096];
    const int t = threadIdx.x, lane = t & 63, w = t >> 6;
    const int wm = w >> 1, wn = w & 1;
    const int m0 = blockIdx.y * 128, n0 = blockIdx.x * 128;
    f32x4 acc[4][4] = {};

    stage128x32(xb, DIM, m0, M1 - 1, 0, sh[0][0]);
    stage128x32(wb, DIM, n0, N3 - 1, 0, sh[0][1]);
    const int nt = DIM / 32;   // 16
    for (int kt = 0; kt < nt; ++kt) {
        int cur = kt & 1;
        __syncthreads();
        if (kt + 1 < nt) {
            stage128x32(xb, DIM, m0, M1 - 1, (kt + 1) * 32, sh[cur ^ 1][0]);
            stage128x32(wb, DIM, n0, N3 - 1, (kt + 1) * 32, sh[cur ^ 1][1]);
        }
        compute_step(sh[cur][0], sh[cur][1], wm, wn, lane, acc);
    }

    const int lr = lane & 15, lq = lane >> 4;
    #pragma unroll
    for (int i = 0; i < 4; ++i) {
        #pragma unroll
        for (int j = 0; j < 4; ++j) {
            #pragma unroll
            for (int q = 0; q < 4; ++q) {
                int m = m0 + wm * 64 + i * 16 + lq * 4 + q;
                if (m >= M1) continue;
                int col = n0 + wn * 64 + j * 16 + lr;
                int b = m / NSEQ, n = m - b * NSEQ;
                int part = col >> 11, within = col & 2047;
                int h = within >> 8, d = within & 255;
                int bh = b * HEADS + h;
                float val = acc[i][j][q];
                size_t idx = ((size_t)bh * NSEQ + n) * DHEAD + d;
                if (part == 0)      qws[idx] = f2b(val * SCALE_F);
                else if (part == 1) kws[idx] = f2b(val);
                else {
                    u16 bv = f2b(val);
                    vws[idx] = bv;
                    vt[((size_t)bh * DHEAD + d) * NSEQ + n] = bv;
                }
            }
        }
    }
}

// =====================================================================
// scores vs k_p: q(all) @ k_p^T -> out1 (rows<284) / out3
// =====================================================================
__global__ void k_scores_kp(const u16* __restrict__ qws, const u16* __restrict__ kws,
                            float* __restrict__ out1, float* __restrict__ out3)
{
    __shared__ u16 sh[2][2][4096];
    const int t = threadIdx.x, lane = t & 63, w = t >> 6;
    const int wm = w >> 1, wn = w & 1;
    const int bh = blockIdx.z;
    const int i0 = blockIdx.y * 128, j0 = blockIdx.x * 128;
    const u16* A = qws + (size_t)bh * NSEQ * DHEAD;
    const u16* B = kws + (size_t)bh * NSEQ * DHEAD;
    f32x4 acc[4][4] = {};

    stage128x32(A, DHEAD, i0, NSEQ - 1, 0, sh[0][0]);
    stage128x32(B, DHEAD, j0, NSEQ - 1, 0, sh[0][1]);
    const int nt = DHEAD / 32;  // 8
    for (int kt = 0; kt < nt; ++kt) {
        int cur = kt & 1;
        __syncthreads();
        if (kt + 1 < nt) {
            stage128x32(A, DHEAD, i0, NSEQ - 1, (kt + 1) * 32, sh[cur ^ 1][0]);
            stage128x32(B, DHEAD, j0, NSEQ - 1, (kt + 1) * 32, sh[cur ^ 1][1]);
        }
        compute_step(sh[cur][0], sh[cur][1], wm, wn, lane, acc);
    }

    const int lr = lane & 15, lq = lane >> 4;
    #pragma unroll
    for (int i = 0; i < 4; ++i) {
        #pragma unroll
        for (int j = 0; j < 4; ++j) {
            #pragma unroll
            for (int q = 0; q < 4; ++q) {
                int ig = i0 + wm * 64 + i * 16 + lq * 4 + q;
                int jg = j0 + wn * 64 + j * 16 + lr;
                if (ig >= NSEQ || jg >= NPATH) continue;
                float val = acc[i][j][q];
                if (ig < NPATH)
                    out1[((size_t)bh * NPATH + ig) * NPATH + jg] = val;
                else
                    out3[((size_t)bh * NHIST + (ig - NPATH)) * NPATH + jg] = val;
            }
        }
    }
}

// =====================================================================
// scores vs k_h: q_p @ k_h^T -> out2
// =====================================================================
__global__ void k_scores_kh(const u16* __restrict__ qws, const u16* __restrict__ kws,
                            float* __restrict__ out2)
{
    __shared__ u16 sh[2][2][4096];
    const int t = threadIdx.x, lane = t & 63, w = t >> 6;
    const int wm = w >> 1, wn = w & 1;
    const int bh = blockIdx.z;
    const int i0 = blockIdx.y * 128, j0 = blockIdx.x * 128;
    const u16* A = qws + (size_t)bh * NSEQ * DHEAD;
    const u16* B = kws + ((size_t)bh * NSEQ + NPATH) * DHEAD;
    f32x4 acc[4][4] = {};

    stage128x32(A, DHEAD, i0, NSEQ - 1, 0, sh[0][0]);
    stage128x32(B, DHEAD, j0, NHIST - 1, 0, sh[0][1]);
    const int nt = DHEAD / 32;
    for (int kt = 0; kt < nt; ++kt) {
        int cur = kt & 1;
        __syncthreads();
        if (kt + 1 < nt) {
            stage128x32(A, DHEAD, i0, NSEQ - 1, (kt + 1) * 32, sh[cur ^ 1][0]);
            stage128x32(B, DHEAD, j0, NHIST - 1, (kt + 1) * 32, sh[cur ^ 1][1]);
        }
        compute_step(sh[cur][0], sh[cur][1], wm, wn, lane, acc);
    }

    const int lr = lane & 15, lq = lane >> 4;
    #pragma unroll
    for (int i = 0; i < 4; ++i) {
        #pragma unroll
        for (int j = 0; j < 4; ++j) {
            #pragma unroll
            for (int q = 0; q < 4; ++q) {
                int ig = i0 + wm * 64 + i * 16 + lq * 4 + q;
                if (ig >= NPATH) continue;
                int jg = j0 + wn * 64 + j * 16 + lr;
                out2[((size_t)bh * NPATH + ig) * NHIST + jg] = acc[i][j][q];
            }
        }
    }
}

// =====================================================================
// softmax row stats
// =====================================================================
__global__ void k_stats2(const float* __restrict__ sc, float* __restrict__ st)
{
    __shared__ float red[4];
    const int row = blockIdx.x;
    const int tid = threadIdx.x;
    const float* p = sc + (size_t)row * NHIST;

    float m = -1e30f;
    for (int j = tid; j < NHIST; j += 256) m = fmaxf(m, p[j]);
    #pragma unroll
    for (int o = 32; o >= 1; o >>= 1) m = fmaxf(m, __shfl_xor(m, o));
    if ((tid & 63) == 0) red[tid >> 6] = m;
    __syncthreads();
    m = fmaxf(fmaxf(red[0], red[1]), fmaxf(red[2], red[3]));

    float s = 0.f;
    for (int j = tid; j < NHIST; j += 256) s += expf(p[j] - m);
    #pragma unroll
    for (int o = 32; o >= 1; o >>= 1) s += __shfl_xor(s, o);
    __syncthreads();
    if ((tid & 63) == 0) red[tid >> 6] = s;
    __syncthreads();
    if (tid == 0) {
        s = red[0] + red[1] + red[2] + red[3];
        st[(size_t)row * 2]     = m;
        st[(size_t)row * 2 + 1] = 1.f / s;
    }
}

__global__ void k_stats3(const float* __restrict__ sc, float* __restrict__ st)
{
    const int row  = blockIdx.x * 4 + (threadIdx.x >> 6);
    const int lane = threadIdx.x & 63;
    const float* p = sc + (size_t)row * NPATH;

    float m = -1e30f;
    for (int j = lane; j < NPATH; j += 64) m = fmaxf(m, p[j]);
    #pragma unroll
    for (int o = 32; o >= 1; o >>= 1) m = fmaxf(m, __shfl_xor(m, o));

    float s = 0.f;
    for (int j = lane; j < NPATH; j += 64) s += expf(p[j] - m);
    #pragma unroll
    for (int o = 32; o >= 1; o >>= 1) s += __shfl_xor(s, o);

    if (lane == 0) {
        st[(size_t)row * 2]     = m;
        st[(size_t)row * 2 + 1] = 1.f / s;
    }
}

// =====================================================================
// PV: out0 = softmax(scores) @ V  (path: mt<3 uses out2/v_h; hist: out3/v_p)
// A reg-staged: exp((sc-m))*inv_s -> bf16 -> ds_write; B via global_load_lds from vt
// =====================================================================
__global__ void k_pv(const float* __restrict__ sc2, const float* __restrict__ st2,
                     const float* __restrict__ sc3, const float* __restrict__ st3,
                     const u16* __restrict__ vt, float* __restrict__ out0)
{
    __shared__ u16 sh[2][2][4096];
    const int t = threadIdx.x, lane = t & 63, w = t >> 6;
    const int wm = w >> 1, wn = w & 1;
    const int bh = blockIdx.z, b = bh >> 3, h = bh & 7;
    const int mt = blockIdx.y;
    const bool isp = (mt < 3);

    const float* sc; const float* st;
    int i0, Klen, rowsmax, seqbase, outbase;
    size_t srow_base;
    if (isp) { sc = sc2; st = st2; i0 = mt * 128;      Klen = NHIST; rowsmax = NPATH - 1;
               seqbase = NPATH; outbase = 0;     srow_base = (size_t)bh * NPATH; }
    else     { sc = sc3; st = st3; i0 = (mt - 3) * 128; Klen = NPATH; rowsmax = NHIST - 1;
               seqbase = 0;     outbase = NPATH; srow_base = (size_t)bh * NHIST; }

    const int n0 = blockIdx.x * 128;
    const u16* vtb = vt + (size_t)bh * DHEAD * NSEQ;
    const int nt = (Klen + 31) / 32;     // 128 or 9
    f32x4 acc[4][4] = {};

    // A staging: P tile [128 rows][32 k] -> bf16 LDS
    auto stageA = [&](int k0, u16* lds) {
        #pragma unroll
        for (int jj = 0; jj < 2; ++jj) {
            int c = jj * 256 + t;
            int r = c >> 2, kg = c & 3;
            int row = i0 + r; if (row > rowsmax) row = rowsmax;
            size_t srow = srow_base + row;
            float mm = st[srow * 2], is = st[srow * 2 + 1];
            const float* p = sc + srow * Klen + k0 + kg * 8;
            bf16x8 vv;
            if (k0 + 32 <= Klen) {
                f32x4 f0 = *(const f32x4*)p;
                f32x4 f1 = *(const f32x4*)(p + 4);
                #pragma unroll
                for (int e = 0; e < 4; ++e) {
                    vv[e]     = (short)f2b(__expf(f0[e] - mm) * is);
                    vv[e + 4] = (short)f2b(__expf(f1[e] - mm) * is);
                }
            } else {
                #pragma unroll
                for (int e = 0; e < 8; ++e) {
                    int kk = k0 + kg * 8 + e;
                    float pv = (kk < Klen) ? __expf(sc[srow * Klen + kk] - mm) * is : 0.f;
                    vv[e] = (short)f2b(pv);
                }
            }
            *(bf16x8*)(lds + (size_t)c * 8) = vv;
        }
    };

    stageA(0, sh[0][0]);
    stage128x32(vtb, NSEQ, n0, DHEAD - 1, seqbase, sh[0][1]);
    for (int kt = 0; kt < nt; ++kt) {
        int cur = kt & 1;
        __syncthreads();
        if (kt + 1 < nt) {
            stageA((kt + 1) * 32, sh[cur ^ 1][0]);
            stage128x32(vtb, NSEQ, n0, DHEAD - 1, seqbase + (kt + 1) * 32, sh[cur ^ 1][1]);
        }
        compute_step(sh[cur][0], sh[cur][1], wm, wn, lane, acc);
    }

    const int lr = lane & 15, lq = lane >> 4;
    #pragma unroll
    for (int i = 0; i < 4; ++i) {
        #pragma unroll
        for (int j = 0; j < 4; ++j) {
            #pragma unroll
            for (int q = 0; q < 4; ++q) {
                int mrow = i0 + wm * 64 + i * 16 + lq * 4 + q;
                if (mrow > rowsmax) continue;
                int d = n0 + wn * 64 + j * 16 + lr;
                out0[((size_t)(b * NSEQ + outbase + mrow)) * INNER + h * DHEAD + d] = acc[i][j][q];
            }
        }
    }
}

// =====================================================================
// depthwise conv over seq, accumulate into out0
// =====================================================================
__global__ void k_conv2(const u16* __restrict__ vws, const float* __restrict__ wconv,
                        float* __restrict__ out0)
{
    __shared__ float lv[64][DHEAD];
    const int bh = blockIdx.z, b = bh >> 3, h = bh & 7;
    const int n0 = blockIdx.y * 32;
    const int d = threadIdx.x;
    const u16* vb = vws + (size_t)bh * NSEQ * DHEAD;

    for (int r = 0; r < 64; ++r) {
        int n = n0 - 16 + r;
        lv[r][d] = (n >= 0 && n < NSEQ) ? b2f(vb[(size_t)n * DHEAD + d]) : 0.f;
    }
    __syncthreads();

    float wc[KSZ];
    #pragma unroll
    for (int tt = 0; tt < KSZ; ++tt) wc[tt] = wconv[h * KSZ + tt];

    for (int i = 0; i < 32; ++i) {
        int n = n0 + i;
        if (n >= NSEQ) break;
        float acc = 0.f;
        #pragma unroll
        for (int tt = 0; tt < KSZ; ++tt) acc += lv[i + tt][d] * wc[tt];
        out0[((size_t)(b * NSEQ + n)) * INNER + h * DHEAD + d] += acc;
    }
}

// =====================================================================
extern "C" void kernel_launch(void* const* d_in, const int* in_sizes, int n_in,
                              void* d_out, int out_size, void* d_ws, size_t ws_size,
                              hipStream_t stream)
{
    const float* x     = (const float*)d_in[0];
    const float* wqkv  = (const float*)d_in[1];
    const float* wconv = (const float*)d_in[2];
    float* out = (float*)d_out;
    char*  ws  = (char*)d_ws;

    u16* xb  = (u16*)(ws + XB_OFF);
    u16* wb  = (u16*)(ws + WB_OFF);
    u16* qws = (u16*)(ws + QW_OFF);
    u16* kws = (u16*)(ws + KW_OFF);
    u16* vws = (u16*)(ws + VW_OFF);
    u16* vt  = (u16*)(ws + VT_OFF);
    float* st2 = (float*)(ws + ST2_OFF);
    float* st3 = (float*)(ws + ST3_OFF);

    float* out0 = out + OUT0_OFF;
    float* out1 = out + OUT1_OFF;
    float* out2 = out + OUT2_OFF;
    float* out3 = out + OUT3_OFF;

    dim3 blk(256);

    // converts
    k_cvt<<<dim3((M1 * DIM / 4 + 255) / 256), blk, 0, stream>>>(x, xb, M1 * DIM / 4);
    k_cvt_wT<<<dim3(N3 / 32, DIM / 32), blk, 0, stream>>>(wqkv, wb);

    // qkv GEMM
    k_qkv<<<dim3(N3 / 128, (M1 + 127) / 128), blk, 0, stream>>>(xb, wb, qws, kws, vws, vt);

    // scores
    k_scores_kp<<<dim3(3, (M1 / NB + 127) / 128, NBH), blk, 0, stream>>>(qws, kws, out1, out3);
    k_scores_kh<<<dim3(NHIST / 128, 3, NBH), blk, 0, stream>>>(qws, kws, out2);

    // stats
    k_stats2<<<dim3(NBH * NPATH), blk, 0, stream>>>(out2, st2);
    k_stats3<<<dim3(NBH * NHIST / 4), blk, 0, stream>>>(out3, st3);

    // PV (path mt 0..2, hist mt 3..34)
    k_pv<<<dim3(2, 35, NBH), blk, 0, stream>>>(out2, st2, out3, st3, vt, out0);

    // conv accumulate
    k_conv2<<<dim3(1, (NSEQ + 31) / 32, NBH), blk, 0, stream>>>(vws, wconv, out0);
}

// Round 6
// 518.677 us; speedup vs baseline: 5.1232x; 1.2586x over previous
//
#include <hip/hip_runtime.h>
#include <math.h>

typedef unsigned short u16;
typedef unsigned int   u32;
typedef __attribute__((ext_vector_type(8))) short bf16x8;
typedef __attribute__((ext_vector_type(4))) float f32x4;
typedef __attribute__((ext_vector_type(4))) u16   u16x4;

// ---------------- problem constants ----------------
#define NB 2
#define NSEQ 4380
#define NPATH 284
#define NHIST 4096
#define DIM 512
#define HEADS 8
#define DHEAD 256
#define INNER 2048
#define N3 6144
#define KSZ 33
#define SCALE_F 0.0625f
#define NBH 16
#define M1 8760   // NB*NSEQ
#define VTHLD 4096
#define VTPLD 288
#define P3LD 288

// ---------------- d_out offsets (floats) ----------------
#define OUT0_OFF 0            // (2,4380,2048)
#define OUT1_OFF 17940480     // attn_pathways (2,8,284,284)
#define OUT2_OFF 19230976     // cross_attn_pathways (2,8,284,4096)
#define OUT3_OFF 37843200     // pre-softmax cross_attn_histology (2,8,4096,284)

// ---------------- ws offsets (bytes) ----------------
// phase A (through scores): xb, wb, qw, kw live
#define XB_OFF   0u                      // bf16 x           [8760][512]
#define WB_OFF   8970240u                // bf16 w^T         [6144][512]
#define QW_OFF   15261696u               // bf16 q head-major[16][4380][256]
#define KW_OFF   51142656u               // bf16 k
// always live
#define VW_OFF   87023616u               // bf16 v  [bh][n][d]       (conv)
#define VTH_OFF  122904576u              // bf16 v_h^T [16][256][4096]
#define VTP_OFF  156459008u              // bf16 v_p^T [16][256][288] (padded)
// phase B (after scores): P matrices alias dead xb/wb/qw/kw
#define P2_OFF   0u                      // bf16 P2 [4544][4096]
#define P3_OFF   37224448u               // bf16 P3 [65536][288] -> ends 74.97MB < 87MB

__device__ __forceinline__ u16 f2b(float f) {
    u32 u = __float_as_uint(f);
    u += 0x7fffu + ((u >> 16) & 1u);
    return (u16)(u >> 16);
}
__device__ __forceinline__ float b2f(u16 u) {
    return __uint_as_float(((u32)u) << 16);
}

__device__ __forceinline__ void async_cp16(const u16* g, u16* l) {
    __builtin_amdgcn_global_load_lds(
        (const __attribute__((address_space(1))) void*)g,
        (__attribute__((address_space(3))) void*)l,
        16, 0, 0);
}

// Stage a 128x32 bf16 tile [row][k] from row-major g (ld elems, 16B-aligned rows)
__device__ __forceinline__ void stage128x32(const u16* __restrict__ g, int ld,
                                            int row0, int rowmax, int k0,
                                            u16* lds)
{
    const int t = threadIdx.x;          // 0..255
    const int w = t >> 6;
    #pragma unroll
    for (int j = 0; j < 2; ++j) {
        int c = j * 256 + t;            // chunk 0..511
        int r = c >> 2, kg = c & 3;
        int row = row0 + r; if (row > rowmax) row = rowmax;
        const u16* gp = g + (size_t)row * ld + k0 + kg * 8;
        async_cp16(gp, lds + (size_t)(j * 256 + w * 64) * 8);
    }
}

// 128x128 block, 4 waves (2x2 of 64x64), one BK=32 step: 4+4 ds_read_b128, 16 MFMA
__device__ __forceinline__ void compute_step(const u16* shA, const u16* shB,
                                             int wm, int wn, int lane,
                                             f32x4 acc[4][4])
{
    const int lr = lane & 15, lk = (lane >> 4) * 8;
    bf16x8 a[4], b[4];
    #pragma unroll
    for (int i = 0; i < 4; ++i)
        a[i] = *(const bf16x8*)(shA + (size_t)(wm * 64 + i * 16 + lr) * 32 + lk);
    #pragma unroll
    for (int j = 0; j < 4; ++j)
        b[j] = *(const bf16x8*)(shB + (size_t)(wn * 64 + j * 16 + lr) * 32 + lk);
    #pragma unroll
    for (int i = 0; i < 4; ++i)
        #pragma unroll
        for (int j = 0; j < 4; ++j)
            acc[i][j] = __builtin_amdgcn_mfma_f32_16x16x32_bf16(a[i], b[j], acc[i][j], 0, 0, 0);
}

// =====================================================================
// converts
// =====================================================================
__global__ void k_cvt(const float* __restrict__ src, u16* __restrict__ dst, int n4)
{
    int i = blockIdx.x * 256 + threadIdx.x;
    if (i >= n4) return;
    f32x4 f = *(const f32x4*)(src + (size_t)i * 4);
    u16x4 o;
    #pragma unroll
    for (int k = 0; k < 4; ++k) o[k] = f2b(f[k]);
    *(u16x4*)(dst + (size_t)i * 4) = o;
}

__global__ void k_cvt_wT(const float* __restrict__ w, u16* __restrict__ wb)
{
    __shared__ float tile[32][33];
    const int n0 = blockIdx.x * 32, k0 = blockIdx.y * 32;
    const int tx = threadIdx.x & 31, ty = threadIdx.x >> 5;   // ty 0..7
    #pragma unroll
    for (int r = 0; r < 32; r += 8)
        tile[ty + r][tx] = w[(size_t)(k0 + ty + r) * N3 + n0 + tx];
    __syncthreads();
    #pragma unroll
    for (int r = 0; r < 32; r += 8)
        wb[(size_t)(n0 + ty + r) * DIM + k0 + tx] = f2b(tile[tx][ty + r]);
}

// =====================================================================
// qkv GEMM: xb[8760][512] @ wb^T -> scatter q/k/v (bf16)
// =====================================================================
__global__ void k_qkv(const u16* __restrict__ xb, const u16* __restrict__ wb,
                      u16* __restrict__ qws, u16* __restrict__ kws,
                      u16* __restrict__ vws)
{
    __shared__ u16 sh[2][2][4096];
    const int t = threadIdx.x, lane = t & 63, w = t >> 6;
    const int wm = w >> 1, wn = w & 1;
    const int m0 = blockIdx.y * 128, n0 = blockIdx.x * 128;
    f32x4 acc[4][4] = {};

    stage128x32(xb, DIM, m0, M1 - 1, 0, sh[0][0]);
    stage128x32(wb, DIM, n0, N3 - 1, 0, sh[0][1]);
    const int nt = DIM / 32;   // 16
    for (int kt = 0; kt < nt; ++kt) {
        int cur = kt & 1;
        __syncthreads();
        if (kt + 1 < nt) {
            stage128x32(xb, DIM, m0, M1 - 1, (kt + 1) * 32, sh[cur ^ 1][0]);
            stage128x32(wb, DIM, n0, N3 - 1, (kt + 1) * 32, sh[cur ^ 1][1]);
        }
        compute_step(sh[cur][0], sh[cur][1], wm, wn, lane, acc);
    }

    const int lr = lane & 15, lq = lane >> 4;
    #pragma unroll
    for (int i = 0; i < 4; ++i) {
        #pragma unroll
        for (int j = 0; j < 4; ++j) {
            #pragma unroll
            for (int q = 0; q < 4; ++q) {
                int m = m0 + wm * 64 + i * 16 + lq * 4 + q;
                if (m >= M1) continue;
                int col = n0 + wn * 64 + j * 16 + lr;
                int b = m / NSEQ, n = m - b * NSEQ;
                int part = col >> 11, within = col & 2047;
                int h = within >> 8, d = within & 255;
                int bh = b * HEADS + h;
                float val = acc[i][j][q];
                size_t idx = ((size_t)bh * NSEQ + n) * DHEAD + d;
                if (part == 0)      qws[idx] = f2b(val * SCALE_F);
                else if (part == 1) kws[idx] = f2b(val);
                else                vws[idx] = f2b(val);
            }
        }
    }
}

// =====================================================================
// transpose v: vws[bh][n][d] -> vtp[bh][d][0..287] (n<284, padded) and
//                              vth[bh][d][0..4095] (n>=284)
// =====================================================================
__global__ void k_vT(const u16* __restrict__ vws, u16* __restrict__ vtp,
                     u16* __restrict__ vth)
{
    __shared__ u16 tile[64][72];
    const int bh = blockIdx.z;
    const int n0 = blockIdx.x * 64, d0 = blockIdx.y * 64;
    const int t = threadIdx.x;

    #pragma unroll
    for (int i = 0; i < 16; ++i) {
        int lin = i * 256 + t;
        int r = lin >> 6, c = lin & 63;
        int n = n0 + r;
        tile[r][c] = (n < NSEQ) ? vws[((size_t)bh * NSEQ + n) * DHEAD + d0 + c] : (u16)0;
    }
    __syncthreads();

    #pragma unroll
    for (int i = 0; i < 16; ++i) {
        int lin = i * 256 + t;
        int r2 = lin >> 6, c2 = lin & 63;     // r2 = d idx, c2 = n idx
        int n = n0 + c2, d = d0 + r2;
        u16 v = tile[c2][r2];
        if (n < NPATH) {
            vtp[((size_t)bh * DHEAD + d) * VTPLD + n] = v;
        } else {
            if (n < NPATH + 4)
                vtp[((size_t)bh * DHEAD + d) * VTPLD + n] = 0;   // zero pad cols 284..287
            if (n < NSEQ)
                vth[((size_t)bh * DHEAD + d) * VTHLD + (n - NPATH)] = v;
        }
    }
}

// =====================================================================
// scores vs k_p: q(all) @ k_p^T -> out1 (rows<284) / out3
// =====================================================================
__global__ void k_scores_kp(const u16* __restrict__ qws, const u16* __restrict__ kws,
                            float* __restrict__ out1, float* __restrict__ out3)
{
    __shared__ u16 sh[2][2][4096];
    const int t = threadIdx.x, lane = t & 63, w = t >> 6;
    const int wm = w >> 1, wn = w & 1;
    const int bh = blockIdx.z;
    const int i0 = blockIdx.y * 128, j0 = blockIdx.x * 128;
    const u16* A = qws + (size_t)bh * NSEQ * DHEAD;
    const u16* B = kws + (size_t)bh * NSEQ * DHEAD;
    f32x4 acc[4][4] = {};

    stage128x32(A, DHEAD, i0, NSEQ - 1, 0, sh[0][0]);
    stage128x32(B, DHEAD, j0, NSEQ - 1, 0, sh[0][1]);
    const int nt = DHEAD / 32;  // 8
    for (int kt = 0; kt < nt; ++kt) {
        int cur = kt & 1;
        __syncthreads();
        if (kt + 1 < nt) {
            stage128x32(A, DHEAD, i0, NSEQ - 1, (kt + 1) * 32, sh[cur ^ 1][0]);
            stage128x32(B, DHEAD, j0, NSEQ - 1, (kt + 1) * 32, sh[cur ^ 1][1]);
        }
        compute_step(sh[cur][0], sh[cur][1], wm, wn, lane, acc);
    }

    const int lr = lane & 15, lq = lane >> 4;
    #pragma unroll
    for (int i = 0; i < 4; ++i) {
        #pragma unroll
        for (int j = 0; j < 4; ++j) {
            #pragma unroll
            for (int q = 0; q < 4; ++q) {
                int ig = i0 + wm * 64 + i * 16 + lq * 4 + q;
                int jg = j0 + wn * 64 + j * 16 + lr;
                if (ig >= NSEQ || jg >= NPATH) continue;
                float val = acc[i][j][q];
                if (ig < NPATH)
                    out1[((size_t)bh * NPATH + ig) * NPATH + jg] = val;
                else
                    out3[((size_t)bh * NHIST + (ig - NPATH)) * NPATH + jg] = val;
            }
        }
    }
}

// =====================================================================
// scores vs k_h: q_p @ k_h^T -> out2
// =====================================================================
__global__ void k_scores_kh(const u16* __restrict__ qws, const u16* __restrict__ kws,
                            float* __restrict__ out2)
{
    __shared__ u16 sh[2][2][4096];
    const int t = threadIdx.x, lane = t & 63, w = t >> 6;
    const int wm = w >> 1, wn = w & 1;
    const int bh = blockIdx.z;
    const int i0 = blockIdx.y * 128, j0 = blockIdx.x * 128;
    const u16* A = qws + (size_t)bh * NSEQ * DHEAD;
    const u16* B = kws + ((size_t)bh * NSEQ + NPATH) * DHEAD;
    f32x4 acc[4][4] = {};

    stage128x32(A, DHEAD, i0, NSEQ - 1, 0, sh[0][0]);
    stage128x32(B, DHEAD, j0, NHIST - 1, 0, sh[0][1]);
    const int nt = DHEAD / 32;
    for (int kt = 0; kt < nt; ++kt) {
        int cur = kt & 1;
        __syncthreads();
        if (kt + 1 < nt) {
            stage128x32(A, DHEAD, i0, NSEQ - 1, (kt + 1) * 32, sh[cur ^ 1][0]);
            stage128x32(B, DHEAD, j0, NHIST - 1, (kt + 1) * 32, sh[cur ^ 1][1]);
        }
        compute_step(sh[cur][0], sh[cur][1], wm, wn, lane, acc);
    }

    const int lr = lane & 15, lq = lane >> 4;
    #pragma unroll
    for (int i = 0; i < 4; ++i) {
        #pragma unroll
        for (int j = 0; j < 4; ++j) {
            #pragma unroll
            for (int q = 0; q < 4; ++q) {
                int ig = i0 + wm * 64 + i * 16 + lq * 4 + q;
                if (ig >= NPATH) continue;
                int jg = j0 + wn * 64 + j * 16 + lr;
                out2[((size_t)bh * NPATH + ig) * NHIST + jg] = acc[i][j][q];
            }
        }
    }
}

// =====================================================================
// softmax: stats + write bf16 P
// =====================================================================
__global__ void k_sm2(const float* __restrict__ sc, u16* __restrict__ p2)
{
    __shared__ float red[4];
    __shared__ float bc[2];
    const int row = blockIdx.x;                 // 4544 rows
    const int tid = threadIdx.x;
    const float* p = sc + (size_t)row * NHIST;

    float m = -1e30f;
    for (int j = tid; j < NHIST; j += 256) m = fmaxf(m, p[j]);
    #pragma unroll
    for (int o = 32; o >= 1; o >>= 1) m = fmaxf(m, __shfl_xor(m, o));
    if ((tid & 63) == 0) red[tid >> 6] = m;
    __syncthreads();
    m = fmaxf(fmaxf(red[0], red[1]), fmaxf(red[2], red[3]));

    float s = 0.f;
    for (int j = tid; j < NHIST; j += 256) s += __expf(p[j] - m);
    #pragma unroll
    for (int o = 32; o >= 1; o >>= 1) s += __shfl_xor(s, o);
    __syncthreads();
    if ((tid & 63) == 0) red[tid >> 6] = s;
    __syncthreads();
    if (tid == 0) {
        s = red[0] + red[1] + red[2] + red[3];
        bc[0] = m; bc[1] = 1.f / s;
    }
    __syncthreads();
    m = bc[0];
    const float inv = bc[1];

    u16* pr = p2 + (size_t)row * NHIST;
    for (int j4 = tid; j4 < NHIST / 4; j4 += 256) {
        f32x4 f = *(const f32x4*)(p + j4 * 4);
        u16x4 o;
        #pragma unroll
        for (int e = 0; e < 4; ++e) o[e] = f2b(__expf(f[e] - m) * inv);
        *(u16x4*)(pr + j4 * 4) = o;
    }
}

__global__ void k_sm3(const float* __restrict__ sc, u16* __restrict__ p3)
{
    const int row  = blockIdx.x * 4 + (threadIdx.x >> 6);   // 65536 rows
    const int lane = threadIdx.x & 63;
    const float* p = sc + (size_t)row * NPATH;

    float m = -1e30f;
    for (int j = lane; j < NPATH; j += 64) m = fmaxf(m, p[j]);
    #pragma unroll
    for (int o = 32; o >= 1; o >>= 1) m = fmaxf(m, __shfl_xor(m, o));

    float s = 0.f;
    for (int j = lane; j < NPATH; j += 64) s += __expf(p[j] - m);
    #pragma unroll
    for (int o = 32; o >= 1; o >>= 1) s += __shfl_xor(s, o);
    const float inv = 1.f / s;

    u16* pr = p3 + (size_t)row * P3LD;
    for (int j = lane; j < P3LD; j += 64) {
        u16 v = 0;
        if (j < NPATH) v = f2b(__expf(p[j] - m) * inv);
        pr[j] = v;
    }
}

// =====================================================================
// PV path: out0 rows 0..283 = P2 @ v_h   (K=4096)
// =====================================================================
__global__ void k_pv_path(const u16* __restrict__ p2, const u16* __restrict__ vth,
                          float* __restrict__ out0)
{
    __shared__ u16 sh[2][2][4096];
    const int t = threadIdx.x, lane = t & 63, w = t >> 6;
    const int wm = w >> 1, wn = w & 1;
    const int bh = blockIdx.z, b = bh >> 3, h = bh & 7;
    const int i0 = blockIdx.y * 128;     // 0..2
    const int d0 = blockIdx.x * 128;     // 0..1
    const u16* A = p2 + (size_t)bh * NPATH * NHIST;
    const u16* B = vth + (size_t)bh * DHEAD * VTHLD;
    f32x4 acc[4][4] = {};

    stage128x32(A, NHIST, i0, NPATH - 1, 0, sh[0][0]);
    stage128x32(B, VTHLD, d0, DHEAD - 1, 0, sh[0][1]);
    const int nt = NHIST / 32;   // 128
    for (int kt = 0; kt < nt; ++kt) {
        int cur = kt & 1;
        __syncthreads();
        if (kt + 1 < nt) {
            stage128x32(A, NHIST, i0, NPATH - 1, (kt + 1) * 32, sh[cur ^ 1][0]);
            stage128x32(B, VTHLD, d0, DHEAD - 1, (kt + 1) * 32, sh[cur ^ 1][1]);
        }
        compute_step(sh[cur][0], sh[cur][1], wm, wn, lane, acc);
    }

    const int lr = lane & 15, lq = lane >> 4;
    #pragma unroll
    for (int i = 0; i < 4; ++i) {
        #pragma unroll
        for (int j = 0; j < 4; ++j) {
            #pragma unroll
            for (int q = 0; q < 4; ++q) {
                int mrow = i0 + wm * 64 + i * 16 + lq * 4 + q;
                if (mrow >= NPATH) continue;
                int d = d0 + wn * 64 + j * 16 + lr;
                out0[((size_t)(b * NSEQ + mrow)) * INNER + h * DHEAD + d] = acc[i][j][q];
            }
        }
    }
}

// =====================================================================
// PV hist: out0 rows 284.. = P3 @ v_p   (K=288 padded)
// =====================================================================
__global__ void k_pv_hist(const u16* __restrict__ p3, const u16* __restrict__ vtp,
                          float* __restrict__ out0)
{
    __shared__ u16 sh[2][2][4096];
    const int t = threadIdx.x, lane = t & 63, w = t >> 6;
    const int wm = w >> 1, wn = w & 1;
    const int bh = blockIdx.z, b = bh >> 3, h = bh & 7;
    const int i0 = blockIdx.y * 128;     // 0..31
    const int d0 = blockIdx.x * 128;     // 0..1
    const u16* A = p3 + (size_t)bh * NHIST * P3LD;
    const u16* B = vtp + (size_t)bh * DHEAD * VTPLD;
    f32x4 acc[4][4] = {};

    stage128x32(A, P3LD, i0, NHIST - 1, 0, sh[0][0]);
    stage128x32(B, VTPLD, d0, DHEAD - 1, 0, sh[0][1]);
    const int nt = P3LD / 32;   // 9
    for (int kt = 0; kt < nt; ++kt) {
        int cur = kt & 1;
        __syncthreads();
        if (kt + 1 < nt) {
            stage128x32(A, P3LD, i0, NHIST - 1, (kt + 1) * 32, sh[cur ^ 1][0]);
            stage128x32(B, VTPLD, d0, DHEAD - 1, (kt + 1) * 32, sh[cur ^ 1][1]);
        }
        compute_step(sh[cur][0], sh[cur][1], wm, wn, lane, acc);
    }

    const int lr = lane & 15, lq = lane >> 4;
    #pragma unroll
    for (int i = 0; i < 4; ++i) {
        #pragma unroll
        for (int j = 0; j < 4; ++j) {
            #pragma unroll
            for (int q = 0; q < 4; ++q) {
                int mrow = i0 + wm * 64 + i * 16 + lq * 4 + q;   // 0..4095
                int d = d0 + wn * 64 + j * 16 + lr;
                out0[((size_t)(b * NSEQ + NPATH + mrow)) * INNER + h * DHEAD + d] = acc[i][j][q];
            }
        }
    }
}

// =====================================================================
// depthwise conv over seq, accumulate into out0
// =====================================================================
__global__ void k_conv2(const u16* __restrict__ vws, const float* __restrict__ wconv,
                        float* __restrict__ out0)
{
    __shared__ float lv[64][DHEAD];
    const int bh = blockIdx.z, b = bh >> 3, h = bh & 7;
    const int n0 = blockIdx.y * 32;
    const int d = threadIdx.x;
    const u16* vb = vws + (size_t)bh * NSEQ * DHEAD;

    for (int r = 0; r < 64; ++r) {
        int n = n0 - 16 + r;
        lv[r][d] = (n >= 0 && n < NSEQ) ? b2f(vb[(size_t)n * DHEAD + d]) : 0.f;
    }
    __syncthreads();

    float wc[KSZ];
    #pragma unroll
    for (int tt = 0; tt < KSZ; ++tt) wc[tt] = wconv[h * KSZ + tt];

    for (int i = 0; i < 32; ++i) {
        int n = n0 + i;
        if (n >= NSEQ) break;
        float acc = 0.f;
        #pragma unroll
        for (int tt = 0; tt < KSZ; ++tt) acc += lv[i + tt][d] * wc[tt];
        out0[((size_t)(b * NSEQ + n)) * INNER + h * DHEAD + d] += acc;
    }
}

// =====================================================================
extern "C" void kernel_launch(void* const* d_in, const int* in_sizes, int n_in,
                              void* d_out, int out_size, void* d_ws, size_t ws_size,
                              hipStream_t stream)
{
    const float* x     = (const float*)d_in[0];
    const float* wqkv  = (const float*)d_in[1];
    const float* wconv = (const float*)d_in[2];
    float* out = (float*)d_out;
    char*  ws  = (char*)d_ws;

    u16* xb  = (u16*)(ws + XB_OFF);
    u16* wb  = (u16*)(ws + WB_OFF);
    u16* qws = (u16*)(ws + QW_OFF);
    u16* kws = (u16*)(ws + KW_OFF);
    u16* vws = (u16*)(ws + VW_OFF);
    u16* vth = (u16*)(ws + VTH_OFF);
    u16* vtp = (u16*)(ws + VTP_OFF);
    u16* p2  = (u16*)(ws + P2_OFF);
    u16* p3  = (u16*)(ws + P3_OFF);

    float* out0 = out + OUT0_OFF;
    float* out1 = out + OUT1_OFF;
    float* out2 = out + OUT2_OFF;
    float* out3 = out + OUT3_OFF;

    dim3 blk(256);

    // converts
    k_cvt<<<dim3((M1 * DIM / 4 + 255) / 256), blk, 0, stream>>>(x, xb, M1 * DIM / 4);
    k_cvt_wT<<<dim3(N3 / 32, DIM / 32), blk, 0, stream>>>(wqkv, wb);

    // qkv GEMM
    k_qkv<<<dim3(N3 / 128, (M1 + 127) / 128), blk, 0, stream>>>(xb, wb, qws, kws, vws);

    // v transpose (after qkv)
    k_vT<<<dim3((NSEQ + 63) / 64, DHEAD / 64, NBH), blk, 0, stream>>>(vws, vtp, vth);

    // scores
    k_scores_kp<<<dim3(3, (NSEQ + 127) / 128, NBH), blk, 0, stream>>>(qws, kws, out1, out3);
    k_scores_kh<<<dim3(NHIST / 128, 3, NBH), blk, 0, stream>>>(qws, kws, out2);

    // softmax -> bf16 P (aliases dead xb/wb/qw/kw regions; stream-ordered after scores)
    k_sm2<<<dim3(NBH * NPATH), blk, 0, stream>>>(out2, p2);
    k_sm3<<<dim3(NBH * NHIST / 4), blk, 0, stream>>>(out3, p3);

    // PV
    k_pv_path<<<dim3(2, 3, NBH), blk, 0, stream>>>(p2, vth, out0);
    k_pv_hist<<<dim3(2, 32, NBH), blk, 0, stream>>>(p3, vtp, out0);

    // conv accumulate
    k_conv2<<<dim3(1, (NSEQ + 31) / 32, NBH), blk, 0, stream>>>(vws, wconv, out0);
}

// Round 7
// 432.855 us; speedup vs baseline: 6.1390x; 1.1983x over previous
//
#include <hip/hip_runtime.h>
#include <math.h>

typedef unsigned short u16;
typedef unsigned int   u32;
typedef __attribute__((ext_vector_type(8))) short bf16x8;
typedef __attribute__((ext_vector_type(4))) float f32x4;
typedef __attribute__((ext_vector_type(4))) u16   u16x4;

// ---------------- problem constants ----------------
#define NB 2
#define NSEQ 4380
#define NPATH 284
#define NHIST 4096
#define DIM 512
#define HEADS 8
#define DHEAD 256
#define INNER 2048
#define N3 6144
#define KSZ 33
#define SCALE_F 0.0625f
#define NBH 16
#define M1 8760   // NB*NSEQ
#define VTHLD 4096
#define VTPLD 288
#define P3LD 288

// ---------------- d_out offsets (floats) ----------------
#define OUT0_OFF 0            // (2,4380,2048)
#define OUT1_OFF 17940480     // attn_pathways (2,8,284,284)
#define OUT2_OFF 19230976     // cross_attn_pathways (2,8,284,4096)
#define OUT3_OFF 37843200     // pre-softmax cross_attn_histology (2,8,4096,284)

// ---------------- ws offsets (bytes) ----------------
// phase A (through scores): xb, wb, qw, kw live
#define XB_OFF   0u                      // bf16 x           [8760][512]
#define WB_OFF   8970240u                // bf16 w^T         [6144][512]
#define QW_OFF   15261696u               // bf16 q head-major[16][4380][256]
#define KW_OFF   51142656u               // bf16 k
// always live
#define VW_OFF   87023616u               // bf16 v  [bh][n][d]       (conv)
#define VTH_OFF  122904576u              // bf16 v_h^T [16][256][4096]
#define VTP_OFF  156459008u              // bf16 v_p^T [16][256][288] (padded)
// phase B (after scores): P matrices alias dead xb/wb/qw/kw
#define P2_OFF   0u                      // bf16 P2 [4544][4096]
#define P3_OFF   37224448u               // bf16 P3 [65536][288] -> ends 74.97MB < 87MB

__device__ __forceinline__ u16 f2b(float f) {
    u32 u = __float_as_uint(f);
    u += 0x7fffu + ((u >> 16) & 1u);
    return (u16)(u >> 16);
}
__device__ __forceinline__ float b2f(u16 u) {
    return __uint_as_float(((u32)u) << 16);
}

__device__ __forceinline__ void async_cp16(const u16* g, u16* l) {
    __builtin_amdgcn_global_load_lds(
        (const __attribute__((address_space(1))) void*)g,
        (__attribute__((address_space(3))) void*)l,
        16, 0, 0);
}

// Stage a 128x32 bf16 tile [row][k] from row-major g (ld elems, 16B-aligned rows)
__device__ __forceinline__ void stage128x32(const u16* __restrict__ g, int ld,
                                            int row0, int rowmax, int k0,
                                            u16* lds)
{
    const int t = threadIdx.x;          // 0..255
    const int w = t >> 6;
    #pragma unroll
    for (int j = 0; j < 2; ++j) {
        int c = j * 256 + t;            // chunk 0..511
        int r = c >> 2, kg = c & 3;
        int row = row0 + r; if (row > rowmax) row = rowmax;
        const u16* gp = g + (size_t)row * ld + k0 + kg * 8;
        async_cp16(gp, lds + (size_t)(j * 256 + w * 64) * 8);
    }
}

// 128x128 block, 4 waves (2x2 of 64x64), one BK=32 step: 4+4 ds_read_b128, 16 MFMA
__device__ __forceinline__ void compute_step(const u16* shA, const u16* shB,
                                             int wm, int wn, int lane,
                                             f32x4 acc[4][4])
{
    const int lr = lane & 15, lk = (lane >> 4) * 8;
    bf16x8 a[4], b[4];
    #pragma unroll
    for (int i = 0; i < 4; ++i)
        a[i] = *(const bf16x8*)(shA + (size_t)(wm * 64 + i * 16 + lr) * 32 + lk);
    #pragma unroll
    for (int j = 0; j < 4; ++j)
        b[j] = *(const bf16x8*)(shB + (size_t)(wn * 64 + j * 16 + lr) * 32 + lk);
    #pragma unroll
    for (int i = 0; i < 4; ++i)
        #pragma unroll
        for (int j = 0; j < 4; ++j)
            acc[i][j] = __builtin_amdgcn_mfma_f32_16x16x32_bf16(a[i], b[j], acc[i][j], 0, 0, 0);
}

// =====================================================================
// converts
// =====================================================================
__global__ void k_cvt(const float* __restrict__ src, u16* __restrict__ dst, int n4)
{
    int i = blockIdx.x * 256 + threadIdx.x;
    if (i >= n4) return;
    f32x4 f = *(const f32x4*)(src + (size_t)i * 4);
    u16x4 o;
    #pragma unroll
    for (int k = 0; k < 4; ++k) o[k] = f2b(f[k]);
    *(u16x4*)(dst + (size_t)i * 4) = o;
}

__global__ void k_cvt_wT(const float* __restrict__ w, u16* __restrict__ wb)
{
    __shared__ float tile[32][33];
    const int n0 = blockIdx.x * 32, k0 = blockIdx.y * 32;
    const int tx = threadIdx.x & 31, ty = threadIdx.x >> 5;   // ty 0..7
    #pragma unroll
    for (int r = 0; r < 32; r += 8)
        tile[ty + r][tx] = w[(size_t)(k0 + ty + r) * N3 + n0 + tx];
    __syncthreads();
    #pragma unroll
    for (int r = 0; r < 32; r += 8)
        wb[(size_t)(n0 + ty + r) * DIM + k0 + tx] = f2b(tile[tx][ty + r]);
}

// =====================================================================
// qkv GEMM: xb[8760][512] @ wb^T -> scatter q/k/v (bf16)
// =====================================================================
__global__ void k_qkv(const u16* __restrict__ xb, const u16* __restrict__ wb,
                      u16* __restrict__ qws, u16* __restrict__ kws,
                      u16* __restrict__ vws)
{
    __shared__ u16 sh[2][2][4096];
    const int t = threadIdx.x, lane = t & 63, w = t >> 6;
    const int wm = w >> 1, wn = w & 1;
    const int m0 = blockIdx.y * 128, n0 = blockIdx.x * 128;
    f32x4 acc[4][4] = {};

    stage128x32(xb, DIM, m0, M1 - 1, 0, sh[0][0]);
    stage128x32(wb, DIM, n0, N3 - 1, 0, sh[0][1]);
    const int nt = DIM / 32;   // 16
    for (int kt = 0; kt < nt; ++kt) {
        int cur = kt & 1;
        __syncthreads();
        if (kt + 1 < nt) {
            stage128x32(xb, DIM, m0, M1 - 1, (kt + 1) * 32, sh[cur ^ 1][0]);
            stage128x32(wb, DIM, n0, N3 - 1, (kt + 1) * 32, sh[cur ^ 1][1]);
        }
        compute_step(sh[cur][0], sh[cur][1], wm, wn, lane, acc);
    }

    const int lr = lane & 15, lq = lane >> 4;
    #pragma unroll
    for (int i = 0; i < 4; ++i) {
        #pragma unroll
        for (int j = 0; j < 4; ++j) {
            #pragma unroll
            for (int q = 0; q < 4; ++q) {
                int m = m0 + wm * 64 + i * 16 + lq * 4 + q;
                if (m >= M1) continue;
                int col = n0 + wn * 64 + j * 16 + lr;
                int b = m / NSEQ, n = m - b * NSEQ;
                int part = col >> 11, within = col & 2047;
                int h = within >> 8, d = within & 255;
                int bh = b * HEADS + h;
                float val = acc[i][j][q];
                size_t idx = ((size_t)bh * NSEQ + n) * DHEAD + d;
                if (part == 0)      qws[idx] = f2b(val * SCALE_F);
                else if (part == 1) kws[idx] = f2b(val);
                else                vws[idx] = f2b(val);
            }
        }
    }
}

// =====================================================================
// transpose v: vws[bh][n][d] -> vtp[bh][d][0..287] (n<284, padded) and
//                              vth[bh][d][0..4095] (n>=284)
// =====================================================================
__global__ void k_vT(const u16* __restrict__ vws, u16* __restrict__ vtp,
                     u16* __restrict__ vth)
{
    __shared__ u16 tile[64][72];
    const int bh = blockIdx.z;
    const int n0 = blockIdx.x * 64, d0 = blockIdx.y * 64;
    const int t = threadIdx.x;

    #pragma unroll
    for (int i = 0; i < 16; ++i) {
        int lin = i * 256 + t;
        int r = lin >> 6, c = lin & 63;
        int n = n0 + r;
        tile[r][c] = (n < NSEQ) ? vws[((size_t)bh * NSEQ + n) * DHEAD + d0 + c] : (u16)0;
    }
    __syncthreads();

    #pragma unroll
    for (int i = 0; i < 16; ++i) {
        int lin = i * 256 + t;
        int r2 = lin >> 6, c2 = lin & 63;     // r2 = d idx, c2 = n idx
        int n = n0 + c2, d = d0 + r2;
        u16 v = tile[c2][r2];
        if (n < NPATH) {
            vtp[((size_t)bh * DHEAD + d) * VTPLD + n] = v;
        } else {
            if (n < NPATH + 4)
                vtp[((size_t)bh * DHEAD + d) * VTPLD + n] = 0;   // zero pad cols 284..287
            if (n < NSEQ)
                vth[((size_t)bh * DHEAD + d) * VTHLD + (n - NPATH)] = v;
        }
    }
}

// =====================================================================
// scores vs k_p: q(all) @ k_p^T -> out1 (rows<284) / out3
// =====================================================================
__global__ void k_scores_kp(const u16* __restrict__ qws, const u16* __restrict__ kws,
                            float* __restrict__ out1, float* __restrict__ out3)
{
    __shared__ u16 sh[2][2][4096];
    const int t = threadIdx.x, lane = t & 63, w = t >> 6;
    const int wm = w >> 1, wn = w & 1;
    const int bh = blockIdx.z;
    const int i0 = blockIdx.y * 128, j0 = blockIdx.x * 128;
    const u16* A = qws + (size_t)bh * NSEQ * DHEAD;
    const u16* B = kws + (size_t)bh * NSEQ * DHEAD;
    f32x4 acc[4][4] = {};

    stage128x32(A, DHEAD, i0, NSEQ - 1, 0, sh[0][0]);
    stage128x32(B, DHEAD, j0, NSEQ - 1, 0, sh[0][1]);
    const int nt = DHEAD / 32;  // 8
    for (int kt = 0; kt < nt; ++kt) {
        int cur = kt & 1;
        __syncthreads();
        if (kt + 1 < nt) {
            stage128x32(A, DHEAD, i0, NSEQ - 1, (kt + 1) * 32, sh[cur ^ 1][0]);
            stage128x32(B, DHEAD, j0, NSEQ - 1, (kt + 1) * 32, sh[cur ^ 1][1]);
        }
        compute_step(sh[cur][0], sh[cur][1], wm, wn, lane, acc);
    }

    const int lr = lane & 15, lq = lane >> 4;
    #pragma unroll
    for (int i = 0; i < 4; ++i) {
        #pragma unroll
        for (int j = 0; j < 4; ++j) {
            #pragma unroll
            for (int q = 0; q < 4; ++q) {
                int ig = i0 + wm * 64 + i * 16 + lq * 4 + q;
                int jg = j0 + wn * 64 + j * 16 + lr;
                if (ig >= NSEQ || jg >= NPATH) continue;
                float val = acc[i][j][q];
                if (ig < NPATH)
                    out1[((size_t)bh * NPATH + ig) * NPATH + jg] = val;
                else
                    out3[((size_t)bh * NHIST + (ig - NPATH)) * NPATH + jg] = val;
            }
        }
    }
}

// =====================================================================
// scores vs k_h: q_p @ k_h^T -> out2
// =====================================================================
__global__ void k_scores_kh(const u16* __restrict__ qws, const u16* __restrict__ kws,
                            float* __restrict__ out2)
{
    __shared__ u16 sh[2][2][4096];
    const int t = threadIdx.x, lane = t & 63, w = t >> 6;
    const int wm = w >> 1, wn = w & 1;
    const int bh = blockIdx.z;
    const int i0 = blockIdx.y * 128, j0 = blockIdx.x * 128;
    const u16* A = qws + (size_t)bh * NSEQ * DHEAD;
    const u16* B = kws + ((size_t)bh * NSEQ + NPATH) * DHEAD;
    f32x4 acc[4][4] = {};

    stage128x32(A, DHEAD, i0, NSEQ - 1, 0, sh[0][0]);
    stage128x32(B, DHEAD, j0, NHIST - 1, 0, sh[0][1]);
    const int nt = DHEAD / 32;
    for (int kt = 0; kt < nt; ++kt) {
        int cur = kt & 1;
        __syncthreads();
        if (kt + 1 < nt) {
            stage128x32(A, DHEAD, i0, NSEQ - 1, (kt + 1) * 32, sh[cur ^ 1][0]);
            stage128x32(B, DHEAD, j0, NHIST - 1, (kt + 1) * 32, sh[cur ^ 1][1]);
        }
        compute_step(sh[cur][0], sh[cur][1], wm, wn, lane, acc);
    }

    const int lr = lane & 15, lq = lane >> 4;
    #pragma unroll
    for (int i = 0; i < 4; ++i) {
        #pragma unroll
        for (int j = 0; j < 4; ++j) {
            #pragma unroll
            for (int q = 0; q < 4; ++q) {
                int ig = i0 + wm * 64 + i * 16 + lq * 4 + q;
                if (ig >= NPATH) continue;
                int jg = j0 + wn * 64 + j * 16 + lr;
                out2[((size_t)bh * NPATH + ig) * NHIST + jg] = acc[i][j][q];
            }
        }
    }
}

// =====================================================================
// softmax: stats + write bf16 P
// =====================================================================
__global__ void k_sm2(const float* __restrict__ sc, u16* __restrict__ p2)
{
    __shared__ float red[4];
    __shared__ float bc[2];
    const int row = blockIdx.x;                 // 4544 rows
    const int tid = threadIdx.x;
    const float* p = sc + (size_t)row * NHIST;

    float m = -1e30f;
    for (int j = tid; j < NHIST; j += 256) m = fmaxf(m, p[j]);
    #pragma unroll
    for (int o = 32; o >= 1; o >>= 1) m = fmaxf(m, __shfl_xor(m, o));
    if ((tid & 63) == 0) red[tid >> 6] = m;
    __syncthreads();
    m = fmaxf(fmaxf(red[0], red[1]), fmaxf(red[2], red[3]));

    float s = 0.f;
    for (int j = tid; j < NHIST; j += 256) s += __expf(p[j] - m);
    #pragma unroll
    for (int o = 32; o >= 1; o >>= 1) s += __shfl_xor(s, o);
    __syncthreads();
    if ((tid & 63) == 0) red[tid >> 6] = s;
    __syncthreads();
    if (tid == 0) {
        s = red[0] + red[1] + red[2] + red[3];
        bc[0] = m; bc[1] = 1.f / s;
    }
    __syncthreads();
    m = bc[0];
    const float inv = bc[1];

    u16* pr = p2 + (size_t)row * NHIST;
    for (int j4 = tid; j4 < NHIST / 4; j4 += 256) {
        f32x4 f = *(const f32x4*)(p + j4 * 4);
        u16x4 o;
        #pragma unroll
        for (int e = 0; e < 4; ++e) o[e] = f2b(__expf(f[e] - m) * inv);
        *(u16x4*)(pr + j4 * 4) = o;
    }
}

__global__ void k_sm3(const float* __restrict__ sc, u16* __restrict__ p3)
{
    const int row  = blockIdx.x * 4 + (threadIdx.x >> 6);   // 65536 rows
    const int lane = threadIdx.x & 63;
    const float* p = sc + (size_t)row * NPATH;

    float m = -1e30f;
    for (int j = lane; j < NPATH; j += 64) m = fmaxf(m, p[j]);
    #pragma unroll
    for (int o = 32; o >= 1; o >>= 1) m = fmaxf(m, __shfl_xor(m, o));

    float s = 0.f;
    for (int j = lane; j < NPATH; j += 64) s += __expf(p[j] - m);
    #pragma unroll
    for (int o = 32; o >= 1; o >>= 1) s += __shfl_xor(s, o);
    const float inv = 1.f / s;

    u16* pr = p3 + (size_t)row * P3LD;
    for (int j = lane; j < P3LD; j += 64) {
        u16 v = 0;
        if (j < NPATH) v = f2b(__expf(p[j] - m) * inv);
        pr[j] = v;
    }
}

// =====================================================================
// PV path: out0 rows 0..283 = P2 @ v_h   (K=4096)
// =====================================================================
__global__ void k_pv_path(const u16* __restrict__ p2, const u16* __restrict__ vth,
                          float* __restrict__ out0)
{
    __shared__ u16 sh[2][2][4096];
    const int t = threadIdx.x, lane = t & 63, w = t >> 6;
    const int wm = w >> 1, wn = w & 1;
    const int bh = blockIdx.z, b = bh >> 3, h = bh & 7;
    const int i0 = blockIdx.y * 128;     // 0..2
    const int d0 = blockIdx.x * 128;     // 0..1
    const u16* A = p2 + (size_t)bh * NPATH * NHIST;
    const u16* B = vth + (size_t)bh * DHEAD * VTHLD;
    f32x4 acc[4][4] = {};

    stage128x32(A, NHIST, i0, NPATH - 1, 0, sh[0][0]);
    stage128x32(B, VTHLD, d0, DHEAD - 1, 0, sh[0][1]);
    const int nt = NHIST / 32;   // 128
    for (int kt = 0; kt < nt; ++kt) {
        int cur = kt & 1;
        __syncthreads();
        if (kt + 1 < nt) {
            stage128x32(A, NHIST, i0, NPATH - 1, (kt + 1) * 32, sh[cur ^ 1][0]);
            stage128x32(B, VTHLD, d0, DHEAD - 1, (kt + 1) * 32, sh[cur ^ 1][1]);
        }
        compute_step(sh[cur][0], sh[cur][1], wm, wn, lane, acc);
    }

    const int lr = lane & 15, lq = lane >> 4;
    #pragma unroll
    for (int i = 0; i < 4; ++i) {
        #pragma unroll
        for (int j = 0; j < 4; ++j) {
            #pragma unroll
            for (int q = 0; q < 4; ++q) {
                int mrow = i0 + wm * 64 + i * 16 + lq * 4 + q;
                if (mrow >= NPATH) continue;
                int d = d0 + wn * 64 + j * 16 + lr;
                out0[((size_t)(b * NSEQ + mrow)) * INNER + h * DHEAD + d] = acc[i][j][q];
            }
        }
    }
}

// =====================================================================
// PV hist: out0 rows 284.. = P3 @ v_p   (K=288 padded)
// =====================================================================
__global__ void k_pv_hist(const u16* __restrict__ p3, const u16* __restrict__ vtp,
                          float* __restrict__ out0)
{
    __shared__ u16 sh[2][2][4096];
    const int t = threadIdx.x, lane = t & 63, w = t >> 6;
    const int wm = w >> 1, wn = w & 1;
    const int bh = blockIdx.z, b = bh >> 3, h = bh & 7;
    const int i0 = blockIdx.y * 128;     // 0..31
    const int d0 = blockIdx.x * 128;     // 0..1
    const u16* A = p3 + (size_t)bh * NHIST * P3LD;
    const u16* B = vtp + (size_t)bh * DHEAD * VTPLD;
    f32x4 acc[4][4] = {};

    stage128x32(A, P3LD, i0, NHIST - 1, 0, sh[0][0]);
    stage128x32(B, VTPLD, d0, DHEAD - 1, 0, sh[0][1]);
    const int nt = P3LD / 32;   // 9
    for (int kt = 0; kt < nt; ++kt) {
        int cur = kt & 1;
        __syncthreads();
        if (kt + 1 < nt) {
            stage128x32(A, P3LD, i0, NHIST - 1, (kt + 1) * 32, sh[cur ^ 1][0]);
            stage128x32(B, VTPLD, d0, DHEAD - 1, (kt + 1) * 32, sh[cur ^ 1][1]);
        }
        compute_step(sh[cur][0], sh[cur][1], wm, wn, lane, acc);
    }

    const int lr = lane & 15, lq = lane >> 4;
    #pragma unroll
    for (int i = 0; i < 4; ++i) {
        #pragma unroll
        for (int j = 0; j < 4; ++j) {
            #pragma unroll
            for (int q = 0; q < 4; ++q) {
                int mrow = i0 + wm * 64 + i * 16 + lq * 4 + q;   // 0..4095
                int d = d0 + wn * 64 + j * 16 + lr;
                out0[((size_t)(b * NSEQ + NPATH + mrow)) * INNER + h * DHEAD + d] = acc[i][j][q];
            }
        }
    }
}

// =====================================================================
// depthwise conv over seq, accumulate into out0
// bf16 LDS [64][256] (32 KB), vectorized staging, register sliding-window FIR
// =====================================================================
__global__ void k_conv3(const u16* __restrict__ vws, const float* __restrict__ wconv,
                        float* __restrict__ out0)
{
    __shared__ u16 lv[64][DHEAD];        // 32 KB bf16
    const int bh = blockIdx.z, b = bh >> 3, h = bh & 7;
    const int n0 = blockIdx.y * 32;
    const int t = threadIdx.x;
    const u16* vb = vws + (size_t)bh * NSEQ * DHEAD;

    // stage rows n0-16 .. n0+47 (64 rows x 256 d), bf16x8 per thread x 8
    #pragma unroll
    for (int i = 0; i < 8; ++i) {
        int oct = i * 256 + t;           // 0..2047
        int r = oct >> 5, o = oct & 31;
        int n = n0 - 16 + r;
        bf16x8 v = {};
        if (n >= 0 && n < NSEQ)
            v = *(const bf16x8*)(vb + (size_t)n * DHEAD + o * 8);
        *(bf16x8*)(&lv[r][o * 8]) = v;
    }
    __syncthreads();

    float wc[KSZ];
    #pragma unroll
    for (int tt = 0; tt < KSZ; ++tt) wc[tt] = wconv[h * KSZ + tt];

    const int d = t;
    // sliding window: win slot (row % 33) holds lv[row][d]
    float win[KSZ];
    #pragma unroll
    for (int j = 0; j < KSZ; ++j) win[j] = b2f(lv[j][d]);

    float* op = out0 + ((size_t)(b * NSEQ + n0)) * INNER + h * DHEAD + d;
    #pragma unroll
    for (int i = 0; i < 32; ++i) {
        if (n0 + i < NSEQ) {
            float acc = 0.f;
            #pragma unroll
            for (int tt = 0; tt < KSZ; ++tt)
                acc += win[(i + tt) % KSZ] * wc[tt];
            op[(size_t)i * INNER] += acc;
        }
        if (i < 31)
            win[i % KSZ] = b2f(lv[i + KSZ][d]);   // slot i: row i -> row i+33
    }
}

// =====================================================================
extern "C" void kernel_launch(void* const* d_in, const int* in_sizes, int n_in,
                              void* d_out, int out_size, void* d_ws, size_t ws_size,
                              hipStream_t stream)
{
    const float* x     = (const float*)d_in[0];
    const float* wqkv  = (const float*)d_in[1];
    const float* wconv = (const float*)d_in[2];
    float* out = (float*)d_out;
    char*  ws  = (char*)d_ws;

    u16* xb  = (u16*)(ws + XB_OFF);
    u16* wb  = (u16*)(ws + WB_OFF);
    u16* qws = (u16*)(ws + QW_OFF);
    u16* kws = (u16*)(ws + KW_OFF);
    u16* vws = (u16*)(ws + VW_OFF);
    u16* vth = (u16*)(ws + VTH_OFF);
    u16* vtp = (u16*)(ws + VTP_OFF);
    u16* p2  = (u16*)(ws + P2_OFF);
    u16* p3  = (u16*)(ws + P3_OFF);

    float* out0 = out + OUT0_OFF;
    float* out1 = out + OUT1_OFF;
    float* out2 = out + OUT2_OFF;
    float* out3 = out + OUT3_OFF;

    dim3 blk(256);

    // converts
    k_cvt<<<dim3((M1 * DIM / 4 + 255) / 256), blk, 0, stream>>>(x, xb, M1 * DIM / 4);
    k_cvt_wT<<<dim3(N3 / 32, DIM / 32), blk, 0, stream>>>(wqkv, wb);

    // qkv GEMM
    k_qkv<<<dim3(N3 / 128, (M1 + 127) / 128), blk, 0, stream>>>(xb, wb, qws, kws, vws);

    // v transpose (after qkv)
    k_vT<<<dim3((NSEQ + 63) / 64, DHEAD / 64, NBH), blk, 0, stream>>>(vws, vtp, vth);

    // scores
    k_scores_kp<<<dim3(3, (NSEQ + 127) / 128, NBH), blk, 0, stream>>>(qws, kws, out1, out3);
    k_scores_kh<<<dim3(NHIST / 128, 3, NBH), blk, 0, stream>>>(qws, kws, out2);

    // softmax -> bf16 P (aliases dead xb/wb/qw/kw regions; stream-ordered after scores)
    k_sm2<<<dim3(NBH * NPATH), blk, 0, stream>>>(out2, p2);
    k_sm3<<<dim3(NBH * NHIST / 4), blk, 0, stream>>>(out3, p3);

    // PV
    k_pv_path<<<dim3(2, 3, NBH), blk, 0, stream>>>(p2, vth, out0);
    k_pv_hist<<<dim3(2, 32, NBH), blk, 0, stream>>>(p3, vtp, out0);

    // conv accumulate
    k_conv3<<<dim3(1, (NSEQ + 31) / 32, NBH), blk, 0, stream>>>(vws, wconv, out0);
}

// Round 8
// 354.393 us; speedup vs baseline: 7.4982x; 1.2214x over previous
//
#include <hip/hip_runtime.h>
#include <math.h>

typedef unsigned short u16;
typedef unsigned int   u32;
typedef __attribute__((ext_vector_type(8))) short bf16x8;
typedef __attribute__((ext_vector_type(4))) float f32x4;
typedef __attribute__((ext_vector_type(4))) u16   u16x4;

// ---------------- problem constants ----------------
#define NB 2
#define NSEQ 4380
#define NPATH 284
#define NHIST 4096
#define DIM 512
#define HEADS 8
#define DHEAD 256
#define INNER 2048
#define N3 6144
#define KSZ 33
#define SCALE_F 0.0625f
#define NBH 16
#define M1 8760   // NB*NSEQ
#define VTHLD 4096
#define VTPLD 288
#define P3LD 288

// ---------------- d_out offsets (floats) ----------------
#define OUT0_OFF 0            // (2,4380,2048)
#define OUT1_OFF 17940480     // attn_pathways (2,8,284,284)
#define OUT2_OFF 19230976     // cross_attn_pathways (2,8,284,4096)
#define OUT3_OFF 37843200     // pre-softmax cross_attn_histology (2,8,4096,284)

// ---------------- ws offsets (bytes) ----------------
// phase A (through scores): xb, wb, qw, kw live
#define XB_OFF   0u                      // bf16 x           [8760][512]
#define WB_OFF   8970240u                // bf16 w^T         [6144][512]
#define QW_OFF   15261696u               // bf16 q head-major[16][4380][256]
#define KW_OFF   51142656u               // bf16 k
// always live
#define VW_OFF   87023616u               // bf16 v  [bh][n][d]       (conv)
#define VTH_OFF  122904576u              // bf16 v_h^T [16][256][4096]
#define VTP_OFF  156459008u              // bf16 v_p^T [16][256][288] (padded)
// phase B (after scores): P matrices alias dead xb/wb/qw/kw
#define P2_OFF   0u                      // bf16 P2 [4544][4096]
#define P3_OFF   37224448u               // bf16 P3 [65536][288] -> ends 74.97MB
// split-K partials for pv_path: f32 [4][16][384][256] = 25.2MB
#define PP_OFF   158818304u              // ends ~184MB < ws size (>=215MB)

__device__ __forceinline__ u16 f2b(float f) {
    u32 u = __float_as_uint(f);
    u += 0x7fffu + ((u >> 16) & 1u);
    return (u16)(u >> 16);
}
__device__ __forceinline__ float b2f(u16 u) {
    return __uint_as_float(((u32)u) << 16);
}

__device__ __forceinline__ void async_cp16(const u16* g, u16* l) {
    __builtin_amdgcn_global_load_lds(
        (const __attribute__((address_space(1))) void*)g,
        (__attribute__((address_space(3))) void*)l,
        16, 0, 0);
}

// Stage a 128x32 bf16 tile [row][k] from row-major g (ld elems, 16B-aligned rows)
__device__ __forceinline__ void stage128x32(const u16* __restrict__ g, int ld,
                                            int row0, int rowmax, int k0,
                                            u16* lds)
{
    const int t = threadIdx.x;          // 0..255
    const int w = t >> 6;
    #pragma unroll
    for (int j = 0; j < 2; ++j) {
        int c = j * 256 + t;            // chunk 0..511
        int r = c >> 2, kg = c & 3;
        int row = row0 + r; if (row > rowmax) row = rowmax;
        const u16* gp = g + (size_t)row * ld + k0 + kg * 8;
        async_cp16(gp, lds + (size_t)(j * 256 + w * 64) * 8);
    }
}

// 128x128 block, 4 waves (2x2 of 64x64), one BK=32 step: 4+4 ds_read_b128, 16 MFMA
__device__ __forceinline__ void compute_step(const u16* shA, const u16* shB,
                                             int wm, int wn, int lane,
                                             f32x4 acc[4][4])
{
    const int lr = lane & 15, lk = (lane >> 4) * 8;
    bf16x8 a[4], b[4];
    #pragma unroll
    for (int i = 0; i < 4; ++i)
        a[i] = *(const bf16x8*)(shA + (size_t)(wm * 64 + i * 16 + lr) * 32 + lk);
    #pragma unroll
    for (int j = 0; j < 4; ++j)
        b[j] = *(const bf16x8*)(shB + (size_t)(wn * 64 + j * 16 + lr) * 32 + lk);
    #pragma unroll
    for (int i = 0; i < 4; ++i)
        #pragma unroll
        for (int j = 0; j < 4; ++j)
            acc[i][j] = __builtin_amdgcn_mfma_f32_16x16x32_bf16(a[i], b[j], acc[i][j], 0, 0, 0);
}

// =====================================================================
// converts
// =====================================================================
__global__ void k_cvt(const float* __restrict__ src, u16* __restrict__ dst, int n4)
{
    int i = blockIdx.x * 256 + threadIdx.x;
    if (i >= n4) return;
    f32x4 f = *(const f32x4*)(src + (size_t)i * 4);
    u16x4 o;
    #pragma unroll
    for (int k = 0; k < 4; ++k) o[k] = f2b(f[k]);
    *(u16x4*)(dst + (size_t)i * 4) = o;
}

__global__ void k_cvt_wT(const float* __restrict__ w, u16* __restrict__ wb)
{
    __shared__ float tile[32][33];
    const int n0 = blockIdx.x * 32, k0 = blockIdx.y * 32;
    const int tx = threadIdx.x & 31, ty = threadIdx.x >> 5;   // ty 0..7
    #pragma unroll
    for (int r = 0; r < 32; r += 8)
        tile[ty + r][tx] = w[(size_t)(k0 + ty + r) * N3 + n0 + tx];
    __syncthreads();
    #pragma unroll
    for (int r = 0; r < 32; r += 8)
        wb[(size_t)(n0 + ty + r) * DIM + k0 + tx] = f2b(tile[tx][ty + r]);
}

// =====================================================================
// qkv GEMM: xb[8760][512] @ wb^T -> scatter q/k/v (bf16)
// =====================================================================
__global__ void k_qkv(const u16* __restrict__ xb, const u16* __restrict__ wb,
                      u16* __restrict__ qws, u16* __restrict__ kws,
                      u16* __restrict__ vws)
{
    __shared__ u16 sh[2][2][4096];
    const int t = threadIdx.x, lane = t & 63, w = t >> 6;
    const int wm = w >> 1, wn = w & 1;
    const int m0 = blockIdx.y * 128, n0 = blockIdx.x * 128;
    f32x4 acc[4][4] = {};

    stage128x32(xb, DIM, m0, M1 - 1, 0, sh[0][0]);
    stage128x32(wb, DIM, n0, N3 - 1, 0, sh[0][1]);
    const int nt = DIM / 32;   // 16
    for (int kt = 0; kt < nt; ++kt) {
        int cur = kt & 1;
        __syncthreads();
        if (kt + 1 < nt) {
            stage128x32(xb, DIM, m0, M1 - 1, (kt + 1) * 32, sh[cur ^ 1][0]);
            stage128x32(wb, DIM, n0, N3 - 1, (kt + 1) * 32, sh[cur ^ 1][1]);
        }
        compute_step(sh[cur][0], sh[cur][1], wm, wn, lane, acc);
    }

    const int lr = lane & 15, lq = lane >> 4;
    #pragma unroll
    for (int i = 0; i < 4; ++i) {
        #pragma unroll
        for (int j = 0; j < 4; ++j) {
            #pragma unroll
            for (int q = 0; q < 4; ++q) {
                int m = m0 + wm * 64 + i * 16 + lq * 4 + q;
                if (m >= M1) continue;
                int col = n0 + wn * 64 + j * 16 + lr;
                int b = m / NSEQ, n = m - b * NSEQ;
                int part = col >> 11, within = col & 2047;
                int h = within >> 8, d = within & 255;
                int bh = b * HEADS + h;
                float val = acc[i][j][q];
                size_t idx = ((size_t)bh * NSEQ + n) * DHEAD + d;
                if (part == 0)      qws[idx] = f2b(val * SCALE_F);
                else if (part == 1) kws[idx] = f2b(val);
                else                vws[idx] = f2b(val);
            }
        }
    }
}

// =====================================================================
// transpose v: vws[bh][n][d] -> vtp[bh][d][0..287] (n<284, padded) and
//                              vth[bh][d][0..4095] (n>=284)
// =====================================================================
__global__ void k_vT(const u16* __restrict__ vws, u16* __restrict__ vtp,
                     u16* __restrict__ vth)
{
    __shared__ u16 tile[64][72];
    const int bh = blockIdx.z;
    const int n0 = blockIdx.x * 64, d0 = blockIdx.y * 64;
    const int t = threadIdx.x;

    #pragma unroll
    for (int i = 0; i < 16; ++i) {
        int lin = i * 256 + t;
        int r = lin >> 6, c = lin & 63;
        int n = n0 + r;
        tile[r][c] = (n < NSEQ) ? vws[((size_t)bh * NSEQ + n) * DHEAD + d0 + c] : (u16)0;
    }
    __syncthreads();

    #pragma unroll
    for (int i = 0; i < 16; ++i) {
        int lin = i * 256 + t;
        int r2 = lin >> 6, c2 = lin & 63;     // r2 = d idx, c2 = n idx
        int n = n0 + c2, d = d0 + r2;
        u16 v = tile[c2][r2];
        if (n < NPATH) {
            vtp[((size_t)bh * DHEAD + d) * VTPLD + n] = v;
        } else {
            if (n < NPATH + 4)
                vtp[((size_t)bh * DHEAD + d) * VTPLD + n] = 0;   // zero pad cols 284..287
            if (n < NSEQ)
                vth[((size_t)bh * DHEAD + d) * VTHLD + (n - NPATH)] = v;
        }
    }
}

// =====================================================================
// scores vs k_p: q(all) @ k_p^T -> out1 (rows<284) / out3
// =====================================================================
__global__ void k_scores_kp(const u16* __restrict__ qws, const u16* __restrict__ kws,
                            float* __restrict__ out1, float* __restrict__ out3)
{
    __shared__ u16 sh[2][2][4096];
    const int t = threadIdx.x, lane = t & 63, w = t >> 6;
    const int wm = w >> 1, wn = w & 1;
    const int bh = blockIdx.z;
    const int i0 = blockIdx.y * 128, j0 = blockIdx.x * 128;
    const u16* A = qws + (size_t)bh * NSEQ * DHEAD;
    const u16* B = kws + (size_t)bh * NSEQ * DHEAD;
    f32x4 acc[4][4] = {};

    stage128x32(A, DHEAD, i0, NSEQ - 1, 0, sh[0][0]);
    stage128x32(B, DHEAD, j0, NSEQ - 1, 0, sh[0][1]);
    const int nt = DHEAD / 32;  // 8
    for (int kt = 0; kt < nt; ++kt) {
        int cur = kt & 1;
        __syncthreads();
        if (kt + 1 < nt) {
            stage128x32(A, DHEAD, i0, NSEQ - 1, (kt + 1) * 32, sh[cur ^ 1][0]);
            stage128x32(B, DHEAD, j0, NSEQ - 1, (kt + 1) * 32, sh[cur ^ 1][1]);
        }
        compute_step(sh[cur][0], sh[cur][1], wm, wn, lane, acc);
    }

    const int lr = lane & 15, lq = lane >> 4;
    #pragma unroll
    for (int i = 0; i < 4; ++i) {
        #pragma unroll
        for (int j = 0; j < 4; ++j) {
            #pragma unroll
            for (int q = 0; q < 4; ++q) {
                int ig = i0 + wm * 64 + i * 16 + lq * 4 + q;
                int jg = j0 + wn * 64 + j * 16 + lr;
                if (ig >= NSEQ || jg >= NPATH) continue;
                float val = acc[i][j][q];
                if (ig < NPATH)
                    out1[((size_t)bh * NPATH + ig) * NPATH + jg] = val;
                else
                    out3[((size_t)bh * NHIST + (ig - NPATH)) * NPATH + jg] = val;
            }
        }
    }
}

// =====================================================================
// scores vs k_h: q_p @ k_h^T -> out2
// =====================================================================
__global__ void k_scores_kh(const u16* __restrict__ qws, const u16* __restrict__ kws,
                            float* __restrict__ out2)
{
    __shared__ u16 sh[2][2][4096];
    const int t = threadIdx.x, lane = t & 63, w = t >> 6;
    const int wm = w >> 1, wn = w & 1;
    const int bh = blockIdx.z;
    const int i0 = blockIdx.y * 128, j0 = blockIdx.x * 128;
    const u16* A = qws + (size_t)bh * NSEQ * DHEAD;
    const u16* B = kws + ((size_t)bh * NSEQ + NPATH) * DHEAD;
    f32x4 acc[4][4] = {};

    stage128x32(A, DHEAD, i0, NSEQ - 1, 0, sh[0][0]);
    stage128x32(B, DHEAD, j0, NHIST - 1, 0, sh[0][1]);
    const int nt = DHEAD / 32;
    for (int kt = 0; kt < nt; ++kt) {
        int cur = kt & 1;
        __syncthreads();
        if (kt + 1 < nt) {
            stage128x32(A, DHEAD, i0, NSEQ - 1, (kt + 1) * 32, sh[cur ^ 1][0]);
            stage128x32(B, DHEAD, j0, NHIST - 1, (kt + 1) * 32, sh[cur ^ 1][1]);
        }
        compute_step(sh[cur][0], sh[cur][1], wm, wn, lane, acc);
    }

    const int lr = lane & 15, lq = lane >> 4;
    #pragma unroll
    for (int i = 0; i < 4; ++i) {
        #pragma unroll
        for (int j = 0; j < 4; ++j) {
            #pragma unroll
            for (int q = 0; q < 4; ++q) {
                int ig = i0 + wm * 64 + i * 16 + lq * 4 + q;
                if (ig >= NPATH) continue;
                int jg = j0 + wn * 64 + j * 16 + lr;
                out2[((size_t)bh * NPATH + ig) * NHIST + jg] = acc[i][j][q];
            }
        }
    }
}

// =====================================================================
// softmax: single global read; row cached in LDS (sm2) / registers (sm3)
// =====================================================================
__global__ void k_sm2(const float* __restrict__ sc, u16* __restrict__ p2)
{
    __shared__ float buf[NHIST];     // 16 KB
    __shared__ float red[4];
    __shared__ float bc[2];
    const int row = blockIdx.x;                 // 4544 rows
    const int tid = threadIdx.x;
    const float* p = sc + (size_t)row * NHIST;

    // stage row (one global pass, vectorized)
    #pragma unroll
    for (int k = 0; k < 4; ++k) {
        int j4 = tid + k * 256;
        ((f32x4*)buf)[j4] = ((const f32x4*)p)[j4];
    }
    __syncthreads();

    float m = -1e30f;
    #pragma unroll
    for (int k = 0; k < 16; ++k) m = fmaxf(m, buf[tid + k * 256]);
    #pragma unroll
    for (int o = 32; o >= 1; o >>= 1) m = fmaxf(m, __shfl_xor(m, o));
    if ((tid & 63) == 0) red[tid >> 6] = m;
    __syncthreads();
    m = fmaxf(fmaxf(red[0], red[1]), fmaxf(red[2], red[3]));

    float s = 0.f;
    #pragma unroll
    for (int k = 0; k < 16; ++k) {
        int j = tid + k * 256;
        float e = __expf(buf[j] - m);
        buf[j] = e;                      // overwrite with exp (reused by write pass)
        s += e;
    }
    #pragma unroll
    for (int o = 32; o >= 1; o >>= 1) s += __shfl_xor(s, o);
    __syncthreads();
    if ((tid & 63) == 0) red[tid >> 6] = s;
    __syncthreads();
    if (tid == 0) bc[0] = 1.f / (red[0] + red[1] + red[2] + red[3]);
    __syncthreads();
    const float inv = bc[0];

    u16* pr = p2 + (size_t)row * NHIST;
    #pragma unroll
    for (int k = 0; k < 4; ++k) {
        int j4 = tid + k * 256;
        f32x4 f = ((const f32x4*)buf)[j4];
        u16x4 o;
        #pragma unroll
        for (int e = 0; e < 4; ++e) o[e] = f2b(f[e] * inv);
        *(u16x4*)(pr + (size_t)j4 * 4) = o;
    }
}

__global__ void k_sm3(const float* __restrict__ sc, u16* __restrict__ p3)
{
    const int row  = blockIdx.x * 4 + (threadIdx.x >> 6);   // 65536 rows
    const int lane = threadIdx.x & 63;
    const float* p = sc + (size_t)row * NPATH;

    // one global pass into registers (5 elems/lane covers 284)
    float v[5];
    #pragma unroll
    for (int k = 0; k < 5; ++k) {
        int j = lane + k * 64;
        v[k] = (j < NPATH) ? p[j] : -1e30f;
    }

    float m = fmaxf(fmaxf(fmaxf(v[0], v[1]), fmaxf(v[2], v[3])), v[4]);
    #pragma unroll
    for (int o = 32; o >= 1; o >>= 1) m = fmaxf(m, __shfl_xor(m, o));

    float s = 0.f;
    #pragma unroll
    for (int k = 0; k < 5; ++k) {
        float e = __expf(v[k] - m);      // pad lanes: exp(-huge)=0
        v[k] = e;
        s += e;
    }
    #pragma unroll
    for (int o = 32; o >= 1; o >>= 1) s += __shfl_xor(s, o);
    const float inv = 1.f / s;

    u16* pr = p3 + (size_t)row * P3LD;
    #pragma unroll
    for (int k = 0; k < 5; ++k) {
        int j = lane + k * 64;
        if (j < P3LD)
            pr[j] = (j < NPATH) ? f2b(v[k] * inv) : (u16)0;
    }
}

// =====================================================================
// PV path split-K: partial[ks] = P2[:, ks*1024:(ks+1)*1024] @ v_h[...]
// pp layout f32 [4][16][384][256]
// =====================================================================
__global__ void k_pv_path_split(const u16* __restrict__ p2, const u16* __restrict__ vth,
                                float* __restrict__ pp)
{
    __shared__ u16 sh[2][2][4096];
    const int t = threadIdx.x, lane = t & 63, w = t >> 6;
    const int wm = w >> 1, wn = w & 1;
    const int z = blockIdx.z;            // bh*4 + ks
    const int bh = z >> 2, ks = z & 3;
    const int i0 = blockIdx.y * 128;     // 0..2
    const int d0 = blockIdx.x * 128;     // 0..1
    const int kb = ks * 1024;
    const u16* A = p2 + (size_t)bh * NPATH * NHIST;
    const u16* B = vth + (size_t)bh * DHEAD * VTHLD;
    f32x4 acc[4][4] = {};

    stage128x32(A, NHIST, i0, NPATH - 1, kb, sh[0][0]);
    stage128x32(B, VTHLD, d0, DHEAD - 1, kb, sh[0][1]);
    const int nt = 32;                   // 1024 / 32
    for (int kt = 0; kt < nt; ++kt) {
        int cur = kt & 1;
        __syncthreads();
        if (kt + 1 < nt) {
            stage128x32(A, NHIST, i0, NPATH - 1, kb + (kt + 1) * 32, sh[cur ^ 1][0]);
            stage128x32(B, VTHLD, d0, DHEAD - 1, kb + (kt + 1) * 32, sh[cur ^ 1][1]);
        }
        compute_step(sh[cur][0], sh[cur][1], wm, wn, lane, acc);
    }

    float* pb = pp + ((size_t)ks * NBH + bh) * 384 * 256;
    const int lr = lane & 15, lq = lane >> 4;
    #pragma unroll
    for (int i = 0; i < 4; ++i) {
        #pragma unroll
        for (int j = 0; j < 4; ++j) {
            #pragma unroll
            for (int q = 0; q < 4; ++q) {
                int mrow = i0 + wm * 64 + i * 16 + lq * 4 + q;   // < 384
                int d = d0 + wn * 64 + j * 16 + lr;
                pb[(size_t)mrow * 256 + d] = acc[i][j][q];
            }
        }
    }
}

// reduce 4 partials -> out0 rows 0..283 (fixed order: deterministic)
__global__ void k_pv_reduce(const float* __restrict__ pp, float* __restrict__ out0)
{
    const int i = blockIdx.x;            // 0..283
    const int bh = blockIdx.y;
    const int d = threadIdx.x;
    const int b = bh >> 3, h = bh & 7;
    const size_t kstr = (size_t)NBH * 384 * 256;
    size_t base = ((size_t)bh * 384 + i) * 256 + d;
    float s = pp[base] + pp[base + kstr] + pp[base + 2 * kstr] + pp[base + 3 * kstr];
    out0[((size_t)(b * NSEQ + i)) * INNER + h * DHEAD + d] = s;
}

// =====================================================================
// PV hist: out0 rows 284.. = P3 @ v_p   (K=288 padded)
// =====================================================================
__global__ void k_pv_hist(const u16* __restrict__ p3, const u16* __restrict__ vtp,
                          float* __restrict__ out0)
{
    __shared__ u16 sh[2][2][4096];
    const int t = threadIdx.x, lane = t & 63, w = t >> 6;
    const int wm = w >> 1, wn = w & 1;
    const int bh = blockIdx.z, b = bh >> 3, h = bh & 7;
    const int i0 = blockIdx.y * 128;     // 0..31
    const int d0 = blockIdx.x * 128;     // 0..1
    const u16* A = p3 + (size_t)bh * NHIST * P3LD;
    const u16* B = vtp + (size_t)bh * DHEAD * VTPLD;
    f32x4 acc[4][4] = {};

    stage128x32(A, P3LD, i0, NHIST - 1, 0, sh[0][0]);
    stage128x32(B, VTPLD, d0, DHEAD - 1, 0, sh[0][1]);
    const int nt = P3LD / 32;   // 9
    for (int kt = 0; kt < nt; ++kt) {
        int cur = kt & 1;
        __syncthreads();
        if (kt + 1 < nt) {
            stage128x32(A, P3LD, i0, NHIST - 1, (kt + 1) * 32, sh[cur ^ 1][0]);
            stage128x32(B, VTPLD, d0, DHEAD - 1, (kt + 1) * 32, sh[cur ^ 1][1]);
        }
        compute_step(sh[cur][0], sh[cur][1], wm, wn, lane, acc);
    }

    const int lr = lane & 15, lq = lane >> 4;
    #pragma unroll
    for (int i = 0; i < 4; ++i) {
        #pragma unroll
        for (int j = 0; j < 4; ++j) {
            #pragma unroll
            for (int q = 0; q < 4; ++q) {
                int mrow = i0 + wm * 64 + i * 16 + lq * 4 + q;   // 0..4095
                int d = d0 + wn * 64 + j * 16 + lr;
                out0[((size_t)(b * NSEQ + NPATH + mrow)) * INNER + h * DHEAD + d] = acc[i][j][q];
            }
        }
    }
}

// =====================================================================
// depthwise conv over seq, accumulate into out0
// bf16 LDS [64][256] (32 KB), vectorized staging, register sliding-window FIR
// =====================================================================
__global__ void k_conv3(const u16* __restrict__ vws, const float* __restrict__ wconv,
                        float* __restrict__ out0)
{
    __shared__ u16 lv[64][DHEAD];        // 32 KB bf16
    const int bh = blockIdx.z, b = bh >> 3, h = bh & 7;
    const int n0 = blockIdx.y * 32;
    const int t = threadIdx.x;
    const u16* vb = vws + (size_t)bh * NSEQ * DHEAD;

    // stage rows n0-16 .. n0+47 (64 rows x 256 d), bf16x8 per thread x 8
    #pragma unroll
    for (int i = 0; i < 8; ++i) {
        int oct = i * 256 + t;           // 0..2047
        int r = oct >> 5, o = oct & 31;
        int n = n0 - 16 + r;
        bf16x8 v = {};
        if (n >= 0 && n < NSEQ)
            v = *(const bf16x8*)(vb + (size_t)n * DHEAD + o * 8);
        *(bf16x8*)(&lv[r][o * 8]) = v;
    }
    __syncthreads();

    float wc[KSZ];
    #pragma unroll
    for (int tt = 0; tt < KSZ; ++tt) wc[tt] = wconv[h * KSZ + tt];

    const int d = t;
    // sliding window: win slot (row % 33) holds lv[row][d]
    float win[KSZ];
    #pragma unroll
    for (int j = 0; j < KSZ; ++j) win[j] = b2f(lv[j][d]);

    float* op = out0 + ((size_t)(b * NSEQ + n0)) * INNER + h * DHEAD + d;
    #pragma unroll
    for (int i = 0; i < 32; ++i) {
        if (n0 + i < NSEQ) {
            float acc = 0.f;
            #pragma unroll
            for (int tt = 0; tt < KSZ; ++tt)
                acc += win[(i + tt) % KSZ] * wc[tt];
            op[(size_t)i * INNER] += acc;
        }
        if (i < 31)
            win[i % KSZ] = b2f(lv[i + KSZ][d]);   // slot i: row i -> row i+33
    }
}

// =====================================================================
extern "C" void kernel_launch(void* const* d_in, const int* in_sizes, int n_in,
                              void* d_out, int out_size, void* d_ws, size_t ws_size,
                              hipStream_t stream)
{
    const float* x     = (const float*)d_in[0];
    const float* wqkv  = (const float*)d_in[1];
    const float* wconv = (const float*)d_in[2];
    float* out = (float*)d_out;
    char*  ws  = (char*)d_ws;

    u16* xb  = (u16*)(ws + XB_OFF);
    u16* wb  = (u16*)(ws + WB_OFF);
    u16* qws = (u16*)(ws + QW_OFF);
    u16* kws = (u16*)(ws + KW_OFF);
    u16* vws = (u16*)(ws + VW_OFF);
    u16* vth = (u16*)(ws + VTH_OFF);
    u16* vtp = (u16*)(ws + VTP_OFF);
    u16* p2  = (u16*)(ws + P2_OFF);
    u16* p3  = (u16*)(ws + P3_OFF);
    float* pp = (float*)(ws + PP_OFF);

    float* out0 = out + OUT0_OFF;
    float* out1 = out + OUT1_OFF;
    float* out2 = out + OUT2_OFF;
    float* out3 = out + OUT3_OFF;

    dim3 blk(256);

    // converts
    k_cvt<<<dim3((M1 * DIM / 4 + 255) / 256), blk, 0, stream>>>(x, xb, M1 * DIM / 4);
    k_cvt_wT<<<dim3(N3 / 32, DIM / 32), blk, 0, stream>>>(wqkv, wb);

    // qkv GEMM
    k_qkv<<<dim3(N3 / 128, (M1 + 127) / 128), blk, 0, stream>>>(xb, wb, qws, kws, vws);

    // v transpose (after qkv)
    k_vT<<<dim3((NSEQ + 63) / 64, DHEAD / 64, NBH), blk, 0, stream>>>(vws, vtp, vth);

    // scores
    k_scores_kp<<<dim3(3, (NSEQ + 127) / 128, NBH), blk, 0, stream>>>(qws, kws, out1, out3);
    k_scores_kh<<<dim3(NHIST / 128, 3, NBH), blk, 0, stream>>>(qws, kws, out2);

    // softmax -> bf16 P (aliases dead xb/wb/qw/kw regions; stream-ordered after scores)
    k_sm2<<<dim3(NBH * NPATH), blk, 0, stream>>>(out2, p2);
    k_sm3<<<dim3(NBH * NHIST / 4), blk, 0, stream>>>(out3, p3);

    // PV path: split-K=4 partials + deterministic reduce
    k_pv_path_split<<<dim3(2, 3, NBH * 4), blk, 0, stream>>>(p2, vth, pp);
    k_pv_reduce<<<dim3(NPATH, NBH), blk, 0, stream>>>(pp, out0);

    // PV hist
    k_pv_hist<<<dim3(2, 32, NBH), blk, 0, stream>>>(p3, vtp, out0);

    // conv accumulate
    k_conv3<<<dim3(1, (NSEQ + 31) / 32, NBH), blk, 0, stream>>>(vws, wconv, out0);
}